// Round 4
// baseline (349.276 us; speedup 1.0000x reference)
//
#include <hip/hip_runtime.h>

#define BN_EPS 1e-5f

typedef __attribute__((ext_vector_type(8))) short bf16x8;
typedef __attribute__((ext_vector_type(4))) float f32x4;

__device__ __forceinline__ unsigned short f2bf(float f) {
    unsigned u = __float_as_uint(f);
    return (unsigned short)((u + 0x7fffu + ((u >> 16) & 1u)) >> 16);   // RNE
}

// ---------------------------------------------------------------------------
// Weight prep (ONE launch): conv3x3 -> wt[tap][co][ci] bf16; 1x1 -> bf16 cast
// grid (252, 10), block 256
// ---------------------------------------------------------------------------
__global__ __launch_bounds__(256)
void prep_weights(const float* __restrict__ w0, const float* __restrict__ w1,
                  const float* __restrict__ w2, const float* __restrict__ w3,
                  const float* __restrict__ w4, unsigned short* __restrict__ dst,
                  const float* __restrict__ v0, const float* __restrict__ v1,
                  const float* __restrict__ v2, const float* __restrict__ v3,
                  const float* __restrict__ v4, unsigned short* __restrict__ dst1)
{
    int z = blockIdx.y;
    int i = blockIdx.x * 256 + threadIdx.x;
    if (z < 5) {
        const float* src; unsigned short* d; int C_out, COP;
        if (z < 3) {
            COP = 64; C_out = 64;
            src = (z == 0) ? w0 : (z == 1 ? w1 : w2);
            d = dst + z * 36864;
            if (i >= 36864) return;
        } else {
            COP = 112; C_out = 100;
            src = (z == 3) ? w3 : w4;
            d = dst + 110592 + (z - 3) * 64512;
            if (i >= 64512) return;
        }
        int tap = i / (COP * 64);
        int rem = i - tap * (COP * 64);
        int co = rem >> 6, ci = rem & 63;
        float v = (co < C_out) ? src[((size_t)co * 64 + ci) * 9 + tap] : 0.f;
        d[i] = f2bf(v);
    } else {
        int zz = z - 5;
        const float* s; int n; int off;
        if (zz == 0)      { s = v0; n = 8192;  off = 0; }
        else if (zz == 1) { s = v1; n = 16384; off = 8192; }
        else if (zz == 2) { s = v2; n = 32768; off = 24576; }
        else if (zz == 3) { s = v3; n = 4096;  off = 57344; }
        else              { s = v4; n = 4096;  off = 61440; }
        if (i >= n) return;
        dst1[off + i] = f2bf(s[i]);
    }
}

// ---------------------------------------------------------------------------
// conv3x3 body v4 (bf16 MFMA 16x16x32, C_in=64, fp32 acc).
// R16: split-K staging — stage 32 channels at a time (LDS 41472 -> 20736 B,
// blocks/CU cap 3 -> 7), accumulators persist across the two K-halves; only
// 9 weight frags live at once.  CPB MUST be 1 (R1/R2: any multi-channel-tile
// loop balloons VGPR 68->180/208 and halves occupancy).
// R17: __launch_bounds__ 4 -> 6 waves/EU. With VGPR=36/LDS=20992 the HW cap
// is 7 blocks/CU but (256,4) pinned us at 4 (measured 44% occ = the cap).
// Grid 1296 = 5.06 blocks/CU now fully co-resident in ONE round.
// ---------------------------------------------------------------------------
template<int COP, int CSPLIT, int MODE>
__device__ __forceinline__
void conv3x3_body(int rem, int TX, unsigned short* xs,
                  const float* __restrict__ x, const unsigned short* __restrict__ wt,
                  const float* __restrict__ p0, const float* __restrict__ p1,
                  const float* __restrict__ p2, const float* __restrict__ p3,
                  float* __restrict__ out, int H, int W, int C_out)
{
    constexpr int NP = 324;
    constexpr int CT = COP / 16;
    static_assert(CT == CSPLIT, "CPB must be 1 (R1/R2 VGPR cliff)");

    int cs = rem % CSPLIT;
    int b  = (rem / CSPLIT) & 3;
    int t  = rem / (CSPLIT * 4);
    int x0 = (t % TX) * 16, y0 = (t / TX) * 16;

    int tid  = threadIdx.x;
    int lane = tid & 63, wid = tid >> 6;
    int lrow = lane >> 4, lcol = lane & 15;
    int HWp = H * W;
    const float* xb = x + (size_t)b * 64 * HWp;

    int co0 = cs * 16;
    bool colok = (x0 + lcol) < W;

    f32x4 accA[2], accB[2];
#pragma unroll
    for (int rr = 0; rr < 2; ++rr) {
        accA[rr] = (f32x4){0.f, 0.f, 0.f, 0.f};
        accB[rr] = (f32x4){0.f, 0.f, 0.f, 0.f};
    }

    unsigned int* wsl = (unsigned int*)xs;

#pragma unroll 1
    for (int kb = 0; kb < 2; ++kb) {
        if (kb) __syncthreads();          // protect xs before overwrite
        // ---- stage channels [kb*32, kb*32+32) of the 18x18 halo tile ----
        for (int p = tid; p < NP; p += 256) {
            int py = p / 18, px = p - py * 18;
            int gy = y0 + py - 1, gx = x0 + px - 1;
            bool ok = (gy >= 0) && (gy < H) && (gx >= 0) && (gx < W);
            const float* gp = xb + (size_t)(kb * 32) * HWp + (size_t)gy * W + gx;
#pragma unroll 8
            for (int cp = 0; cp < 16; ++cp) {
                float v0 = 0.f, v1 = 0.f;
                if (ok) {
                    v0 = gp[(size_t)(2 * cp) * HWp];
                    v1 = gp[(size_t)(2 * cp + 1) * HWp];
                }
                unsigned pk = ((unsigned)f2bf(v1) << 16) | (unsigned)f2bf(v0);
                wsl[((cp >> 2) * NP + p) * 4 + (cp & 3)] = pk;
            }
        }
        __syncthreads();

        // ---- weights for this K-half: 9 taps x 1 frag ----
        bf16x8 a[9];
        const unsigned short* wl = wt + ((size_t)co0 + lcol) * 64 + kb * 32 + lrow * 8;
#pragma unroll
        for (int t9 = 0; t9 < 9; ++t9)
            a[t9] = *(const bf16x8*)(wl + (size_t)t9 * COP * 64);

        // ---- 18 MFMAs into persistent accumulators ----
#pragma unroll
        for (int rr = 0; rr < 2; ++rr) {
            int r0 = wid + rr * 8;
#pragma unroll
            for (int t9 = 0; t9 < 9; ++t9) {
                int dy = t9 / 3, dx = t9 - dy * 3;
                int g0 = lrow * NP + (r0 + dy) * 18 + lcol + dx;
                bf16x8 b0 = *(const bf16x8*)(xs + (size_t)g0 * 8);
                accA[rr] = __builtin_amdgcn_mfma_f32_16x16x32_bf16(a[t9], b0, accA[rr], 0, 0, 0);
                bf16x8 b1 = *(const bf16x8*)(xs + ((size_t)g0 + 4 * 18) * 8);
                accB[rr] = __builtin_amdgcn_mfma_f32_16x16x32_bf16(a[t9], b1, accB[rr], 0, 0, 0);
            }
        }
    }

    // ---- epilogue: BN/bias + store ----
    float sc[4], sh[4];
#pragma unroll
    for (int rg = 0; rg < 4; ++rg) {
        int co = co0 + lrow * 4 + rg;
        int cc = (co < C_out) ? co : 0;
        if (MODE == 0) { sc[rg] = 1.f; sh[rg] = p0[cc]; }
        else {
            float inv = p0[cc] * rsqrtf(p3[cc] + BN_EPS);
            sc[rg] = inv; sh[rg] = p1[cc] - p2[cc] * inv;
        }
    }
#pragma unroll
    for (int rr = 0; rr < 2; ++rr) {
        int r0 = wid + rr * 8;
        int yA = y0 + r0, yB = y0 + r0 + 4;
#pragma unroll
        for (int rg = 0; rg < 4; ++rg) {
            int co = co0 + lrow * 4 + rg;
            if (colok && co < C_out) {
                float* oc = out + (((size_t)b * C_out + co) * H) * W + x0 + lcol;
                if (yA < H) oc[(size_t)yA * W] = accA[rr][rg] * sc[rg] + sh[rg];
                if (yB < H) oc[(size_t)yB * W] = accB[rr][rg] * sc[rg] + sh[rg];
            }
        }
    }
}

// standalone conv3x3 (enc layers), grid (TX, TY, B*CSPLIT)
template<int COP, int CSPLIT, int MODE>
__global__ __launch_bounds__(256, 6)
void conv3x3_mfma(const float* __restrict__ x, const unsigned short* __restrict__ wt,
                  const float* __restrict__ p0, const float* __restrict__ p1,
                  const float* __restrict__ p2, const float* __restrict__ p3,
                  float* __restrict__ out, int H, int W, int C_out)
{
    __shared__ unsigned short xs[4 * 324 * 8];
    int TX = gridDim.x;
    int cs = blockIdx.z % CSPLIT;
    int b  = blockIdx.z / CSPLIT;
    int flat = (((blockIdx.y * TX + blockIdx.x) * 4 + b) * CSPLIT) + cs;
    conv3x3_body<COP, CSPLIT, MODE>(flat, TX, xs, x, wt, p0, p1, p2, p3, out, H, W, C_out);
}

// fused fpn: SINGLE <64,4,0> instantiation, split-K staging body.
// level0: [0,960)  level1: [960,1200)  level2: [1200,1296).  grid (1296)
__global__ __launch_bounds__(256, 6)
void fpn_multi(const float* __restrict__ l0, const unsigned short* __restrict__ wt0,
               const float* __restrict__ b0, float* __restrict__ o0,
               const float* __restrict__ l1, const unsigned short* __restrict__ wt1,
               const float* __restrict__ b1, float* __restrict__ o1,
               const float* __restrict__ l2, const unsigned short* __restrict__ wt2,
               const float* __restrict__ b2, float* __restrict__ o2)
{
    __shared__ unsigned short xs[4 * 324 * 8];
    int f = blockIdx.x;
    const float* x; const unsigned short* wt; const float* bias; float* o;
    int H, W, TX, rem;
    if (f < 960)       { x = l0; wt = wt0; bias = b0; o = o0; H = 96; W = 160; TX = 10; rem = f; }
    else if (f < 1200) { x = l1; wt = wt1; bias = b1; o = o1; H = 48; W = 80;  TX = 5;  rem = f - 960; }
    else               { x = l2; wt = wt2; bias = b2; o = o2; H = 24; W = 40;  TX = 3;  rem = f - 1200; }
    conv3x3_body<64, 4, 0>(rem, TX, xs, x, wt, bias, nullptr, nullptr, nullptr, o, H, W, 64);
}

// ---------------------------------------------------------------------------
// conv1x1 body (bf16 MFMA GEMM).  xs = 4*NPX*8 shorts of LDS.
// ---------------------------------------------------------------------------
template<int C_IN, int KSPLIT, int NPX, int MODE>
__device__ __forceinline__
void conv1x1_body(int f, unsigned short* xs,
                  const float* __restrict__ x, const unsigned short* __restrict__ wb,
                  const float* __restrict__ p0, const float* __restrict__ p1,
                  const float* __restrict__ p2, const float* __restrict__ p3,
                  float* __restrict__ out, int HW)
{
    constexpr int NT = NPX / 16;
    constexpr int KLEN = C_IN / KSPLIT;
    int nb = HW / NPX;
    int px0 = (f % nb) * NPX;
    int ks  = (f / nb) % KSPLIT;
    int b   = f / (nb * KSPLIT);

    int tid = threadIdx.x;
    int lane = tid & 63, wid = tid >> 6;
    int lrow = lane >> 4, lcol = lane & 15;
    const float* xb = x + (size_t)b * C_IN * HW + px0;

    f32x4 acc[NT];
#pragma unroll
    for (int nt = 0; nt < NT; ++nt) acc[nt] = (f32x4){0.f, 0.f, 0.f, 0.f};

    for (int cc = 0; cc < KLEN; cc += 32) {
        if (cc) __syncthreads();
        int cb = ks * KLEN + cc;
#pragma unroll
        for (int t = 0; t < NPX / 16; ++t) {
            int i = tid + t * 256;
            int px = i & (NPX - 1);
            int cp = i / NPX;
            float v0 = xb[(size_t)(cb + 2 * cp) * HW + px];
            float v1 = xb[(size_t)(cb + 2 * cp + 1) * HW + px];
            unsigned pk = ((unsigned)f2bf(v1) << 16) | (unsigned)f2bf(v0);
            ((unsigned*)xs)[((cp >> 2) * NPX + px) * 4 + (cp & 3)] = pk;
        }
        __syncthreads();

        bf16x8 a = *(const bf16x8*)(wb + (size_t)(wid * 16 + lcol) * C_IN + cb + lrow * 8);
#pragma unroll
        for (int nt = 0; nt < NT; ++nt) {
            bf16x8 bf = *(const bf16x8*)(xs + ((size_t)lrow * NPX + nt * 16 + lcol) * 8);
            acc[nt] = __builtin_amdgcn_mfma_f32_16x16x32_bf16(a, bf, acc[nt], 0, 0, 0);
        }
    }

    if (KSPLIT == 1) {
#pragma unroll
        for (int rg = 0; rg < 4; ++rg) {
            int co = wid * 16 + lrow * 4 + rg;
            float scale, shift;
            if (MODE == 0) { scale = 1.f; shift = p0[co]; }
            else {
                float inv = p0[co] * rsqrtf(p3[co] + BN_EPS);
                scale = inv; shift = p1[co] - p2[co] * inv;
            }
            float* op = out + ((size_t)(b * 64 + co)) * HW + px0;
#pragma unroll
            for (int nt = 0; nt < NT; ++nt) {
                float r = acc[nt][rg] * scale + shift;
                if (MODE == 1) r = fmaxf(r, 0.f);
                op[nt * 16 + lcol] = r;
            }
        }
    } else {
#pragma unroll
        for (int rg = 0; rg < 4; ++rg) {
            int co = wid * 16 + lrow * 4 + rg;
            float* op = out + (((size_t)(ks * 4 + b)) * 64 + co) * HW + px0;
#pragma unroll
            for (int nt = 0; nt < NT; ++nt)
                op[nt * 16 + lcol] = acc[nt][rg];
        }
    }
}

// standalone conv1x1 (comp layers), grid (HW/NPX, 1, B)
template<int C_IN, int KSPLIT, int NPX, int MODE>
__global__ __launch_bounds__(256, 4)
void conv1x1_mfma(const float* __restrict__ x, const unsigned short* __restrict__ wb,
                  const float* __restrict__ p0, const float* __restrict__ p1,
                  const float* __restrict__ p2, const float* __restrict__ p3,
                  float* __restrict__ out, int HW)
{
    __shared__ __align__(16) unsigned short xs[4 * NPX * 8];
    int nb = HW / NPX;
    int f = blockIdx.x + nb * (blockIdx.y + KSPLIT * blockIdx.z);
    conv1x1_body<C_IN, KSPLIT, NPX, MODE>(f, xs, x, wb, p0, p1, p2, p3, out, HW);
}

// fused lateral convs: lat0 [0,480), lat1->part [480,720), lat2->part [720,960)
__global__ __launch_bounds__(256, 4)
void lat_multi(const float* __restrict__ x0, const unsigned short* __restrict__ w0,
               const float* __restrict__ b0, float* __restrict__ lat0,
               const float* __restrict__ x1, const unsigned short* __restrict__ w1,
               float* __restrict__ part1,
               const float* __restrict__ x2, const unsigned short* __restrict__ w2,
               float* __restrict__ part2)
{
    __shared__ __align__(16) unsigned short xs[4 * 128 * 8];
    int f = blockIdx.x;
    if (f < 480)
        conv1x1_body<128, 1, 128, 0>(f, xs, x0, w0, b0, nullptr, nullptr, nullptr, lat0, 15360);
    else if (f < 720)
        conv1x1_body<256, 2, 128, 0>(f - 480, xs, x1, w1, nullptr, nullptr, nullptr, nullptr, part1, 3840);
    else
        conv1x1_body<512, 4, 64, 0>(f - 720, xs, x2, w2, nullptr, nullptr, nullptr, nullptr, part2, 960);
}

// ---------------------------------------------------------------------------
// fused K-split reduce + bias: lat1 blocks [0,960), lat2 blocks [960,1200)
// ---------------------------------------------------------------------------
template<int KSPLIT>
__device__ __forceinline__
void reduce_body(int f, const float* __restrict__ part, const float* __restrict__ bias,
                 float* __restrict__ out, int HW, int N4)
{
    int i = f * 256 + threadIdx.x;
    if (i >= N4) return;
    size_t base = (size_t)i * 4;
    int co = (int)((base / (size_t)HW) & 63);
    size_t stride = (size_t)HW << 8;
    float4 s = *(const float4*)(part + base);
#pragma unroll
    for (int ks = 1; ks < KSPLIT; ++ks) {
        float4 t = *(const float4*)(part + (size_t)ks * stride + base);
        s.x += t.x; s.y += t.y; s.z += t.z; s.w += t.w;
    }
    float bv = bias[co];
    s.x += bv; s.y += bv; s.z += bv; s.w += bv;
    *(float4*)(out + base) = s;
}

__global__ __launch_bounds__(256)
void reduce_multi(const float* __restrict__ part1, const float* __restrict__ b1,
                  float* __restrict__ lat1,
                  const float* __restrict__ part2, const float* __restrict__ b2,
                  float* __restrict__ lat2)
{
    int f = blockIdx.x;
    if (f < 960) reduce_body<2>(f, part1, b1, lat1, 3840, 245760);
    else         reduce_body<4>(f - 960, part2, b2, lat2, 960, 61440);
}

// ---------------------------------------------------------------------------
// CARAFE v4 (channel-group split).  R17: launch bounds 4 -> 6 waves/EU
// (LDS 20736 allows 7 blocks/CU; VGPR ~60 fits 6 waves/EU budget ~85).
// grid: (2w/16, 2h/16, B * CGS), block 256
// ---------------------------------------------------------------------------
template<int CGS>
__global__ __launch_bounds__(256, 6)
void carafe_kernel(const float* __restrict__ src, const float* __restrict__ logits,
                   float* __restrict__ dst, int h, int w)
{
    constexpr int SW = 12, NPX = 144;
    constexpr int CH = 64 / CGS;
    constexpr int CS = CH + 4;
    __shared__ float ls[NPX * CS];

    int tid = threadIdx.x;
    int x0 = blockIdx.x * 16, y0 = blockIdx.y * 16;
    int b  = blockIdx.z / CGS;
    int cs = blockIdx.z % CGS;
    int H = 2 * h, W = 2 * w;
    int xs0 = (x0 >> 1) - 2, ys0 = (y0 >> 1) - 2;
    size_t hw = (size_t)h * w;
    const float* sb = src + ((size_t)(b * 64 + cs * CH)) * hw;

    for (int i = tid; i < NPX * CH; i += 256) {
        int c = i / NPX, p = i - c * NPX;
        int yy = p / SW, xx = p - yy * SW;
        int sy = ys0 + yy, sx = xs0 + xx;
        float v = 0.f;
        if (sy >= 0 && sy < h && sx >= 0 && sx < w)
            v = sb[(size_t)c * hw + (size_t)sy * w + sx];
        ls[p * CS + c] = v;
    }
    __syncthreads();

    int lx = tid & 15, ty = tid >> 4;
    int x = x0 + lx, y = y0 + ty;
    int xw = x >> 1, yh = y >> 1;
    int par = (y & 1) * 2 + (x & 1);

    const float* lp = logits + ((size_t)(b * 100 + par) * h + yh) * w + xw;
    float l[25];
    float mx = -1e30f;
#pragma unroll
    for (int k = 0; k < 25; ++k) {
        l[k] = lp[(size_t)(4 * k) * hw];
        mx = fmaxf(mx, l[k]);
    }
    float s = 0.f;
#pragma unroll
    for (int k = 0; k < 25; ++k) {
        l[k] = __expf(l[k] - mx);
        s += l[k];
    }
    float invs = 1.f / s;
#pragma unroll
    for (int k = 0; k < 25; ++k) l[k] *= invs;

    int pb = (yh - ys0 - 2) * SW + (xw - xs0 - 2);

#pragma unroll 1
    for (int cg = 0; cg < CH / 16; ++cg) {
        float acc[16];
#pragma unroll
        for (int c = 0; c < 16; ++c) acc[c] = 0.f;
#pragma unroll
        for (int k = 0; k < 25; ++k) {
            int ti = k / 5, tj = k - ti * 5;
            const float* q = &ls[(pb + ti * SW + tj) * CS + cg * 16];
            float wk = l[k];
#pragma unroll
            for (int c = 0; c < 16; ++c)
                acc[c] = fmaf(wk, q[c], acc[c]);
        }
        float* dp = dst + (((size_t)(b * 64 + cs * CH + cg * 16)) * H + y) * W + x;
#pragma unroll
        for (int c = 0; c < 16; ++c)
            dp[(size_t)c * H * W] += acc[c];
    }
}

// ---------------------------------------------------------------------------
extern "C" void kernel_launch(void* const* d_in, const int* in_sizes, int n_in,
                              void* d_out, int out_size, void* d_ws, size_t ws_size,
                              hipStream_t stream)
{
    const float* x0      = (const float*)d_in[0];
    const float* lat0_w  = (const float*)d_in[1];
    const float* lat0_b  = (const float*)d_in[2];
    const float* fpn0_w  = (const float*)d_in[3];
    const float* fpn0_b  = (const float*)d_in[4];
    const float* x1      = (const float*)d_in[5];
    const float* lat1_w  = (const float*)d_in[6];
    const float* lat1_b  = (const float*)d_in[7];
    const float* fpn1_w  = (const float*)d_in[8];
    const float* fpn1_b  = (const float*)d_in[9];
    const float* x2      = (const float*)d_in[10];
    const float* lat2_w  = (const float*)d_in[11];
    const float* lat2_b  = (const float*)d_in[12];
    const float* fpn2_w  = (const float*)d_in[13];
    const float* fpn2_b  = (const float*)d_in[14];
    const float* u0_comp_w = (const float*)d_in[15];
    const float* u0_enc_w  = (const float*)d_in[16];
    const float* u0_comp_g  = (const float*)d_in[17];
    const float* u0_comp_bt = (const float*)d_in[18];
    const float* u0_comp_m  = (const float*)d_in[19];
    const float* u0_comp_v  = (const float*)d_in[20];
    const float* u0_enc_g   = (const float*)d_in[21];
    const float* u0_enc_bt  = (const float*)d_in[22];
    const float* u0_enc_m   = (const float*)d_in[23];
    const float* u0_enc_v   = (const float*)d_in[24];
    const float* u1_comp_w = (const float*)d_in[25];
    const float* u1_enc_w  = (const float*)d_in[26];
    const float* u1_comp_g  = (const float*)d_in[27];
    const float* u1_comp_bt = (const float*)d_in[28];
    const float* u1_comp_m  = (const float*)d_in[29];
    const float* u1_comp_v  = (const float*)d_in[30];
    const float* u1_enc_g   = (const float*)d_in[31];
    const float* u1_enc_bt  = (const float*)d_in[32];
    const float* u1_enc_m   = (const float*)d_in[33];
    const float* u1_enc_v   = (const float*)d_in[34];

    float* out = (float*)d_out;
    const size_t OUT0 = 4ull * 64 * 96 * 160;   // 3,932,160
    const size_t OUT1 = 4ull * 64 * 48 * 80;    //   983,040
    const size_t OUT2 = 4ull * 64 * 24 * 40;    //   245,760
    float* out0 = out;
    float* out1 = out + OUT0;
    float* out2 = out + OUT0 + OUT1;

    float* lat0 = (float*)d_ws;
    float* lat1 = lat0 + OUT0;
    float* lat2 = lat1 + OUT1;
    unsigned short* wtb = (unsigned short*)(lat2 + OUT2);   // 239,616 bf16
    unsigned short* wt_fpn0 = wtb;
    unsigned short* wt_fpn1 = wtb + 36864;
    unsigned short* wt_fpn2 = wtb + 73728;
    unsigned short* wt_enc0 = wtb + 110592;
    unsigned short* wt_enc1 = wtb + 175104;
    unsigned short* wb = wtb + 239616;                      // 65,536 bf16 (1x1)
    unsigned short* wb_lat0  = wb;
    unsigned short* wb_lat1  = wb + 8192;
    unsigned short* wb_lat2  = wb + 24576;
    unsigned short* wb_comp0 = wb + 57344;
    unsigned short* wb_comp1 = wb + 61440;
    // out0 region doubles as scratch (fpn_multi overwrites it LAST):
    float* part1 = out0;                 // lat1 partials: 2*983,040
    float* part2 = out0 + 2 * OUT1;      // lat2 partials: 4*245,760
    float* comp  = out0;                 // comp logits (after reduces consume parts)
    float* enc   = out0 + OUT1;          // enc logits

    dim3 blk(256);

    // 0) weight prep
    prep_weights<<<dim3(252, 10), blk, 0, stream>>>(
        fpn0_w, fpn1_w, fpn2_w, u0_enc_w, u1_enc_w, wtb,
        lat0_w, lat1_w, lat2_w, u0_comp_w, u1_comp_w, wb);

    // 1) all three lateral 1x1 convs — ONE dispatch (960 blocks)
    lat_multi<<<dim3(960), blk, 0, stream>>>(
        x0, wb_lat0, lat0_b, lat0, x1, wb_lat1, part1, x2, wb_lat2, part2);

    // 2) both K-split reduces — ONE dispatch (1200 blocks)
    reduce_multi<<<dim3(1200), blk, 0, stream>>>(
        part1, lat1_b, lat1, part2, lat2_b, lat2);

    // 3) CARAFE u1: lat1 += carafe(lat2)
    conv1x1_mfma<64, 1, 32, 1><<<dim3(30, 1, 4), blk, 0, stream>>>(
        lat2, wb_comp1, u1_comp_g, u1_comp_bt, u1_comp_m, u1_comp_v, comp, 24 * 40);
    conv3x3_mfma<112, 7, 1><<<dim3(3, 2, 28), blk, 0, stream>>>(
        comp, wt_enc1, u1_enc_g, u1_enc_bt, u1_enc_m, u1_enc_v, enc, 24, 40, 100);
    carafe_kernel<2><<<dim3(5, 3, 8), blk, 0, stream>>>(lat2, enc, lat1, 24, 40);

    // 4) CARAFE u0: lat0 += carafe(lat1)
    conv1x1_mfma<64, 1, 128, 1><<<dim3(30, 1, 4), blk, 0, stream>>>(
        lat1, wb_comp0, u0_comp_g, u0_comp_bt, u0_comp_m, u0_comp_v, comp, 48 * 80);
    conv3x3_mfma<112, 7, 1><<<dim3(5, 3, 28), blk, 0, stream>>>(
        comp, wt_enc0, u0_enc_g, u0_enc_bt, u0_enc_m, u0_enc_v, enc, 48, 80, 100);
    carafe_kernel<2><<<dim3(10, 6, 8), blk, 0, stream>>>(lat1, enc, lat0, 48, 80);

    // 5) all three output 3x3 convs — ONE dispatch, single instantiation
    fpn_multi<<<dim3(1296), blk, 0, stream>>>(
        lat0, wt_fpn0, fpn0_b, out0,
        lat1, wt_fpn1, fpn1_b, out1,
        lat2, wt_fpn2, fpn2_b, out2);
}

// Round 5
// 327.193 us; speedup vs baseline: 1.0675x; 1.0675x over previous
//
#include <hip/hip_runtime.h>

#define BN_EPS 1e-5f

typedef __attribute__((ext_vector_type(8))) short bf16x8;
typedef __attribute__((ext_vector_type(4))) float f32x4;

__device__ __forceinline__ unsigned short f2bf(float f) {
    unsigned u = __float_as_uint(f);
    return (unsigned short)((u + 0x7fffu + ((u >> 16) & 1u)) >> 16);   // RNE
}
__device__ __forceinline__ unsigned packbf(float lo, float hi) {
    return ((unsigned)f2bf(hi) << 16) | (unsigned)f2bf(lo);
}

// ---------------------------------------------------------------------------
// Weight prep (ONE launch): conv3x3 -> wt[tap][co][ci] bf16; 1x1 -> bf16 cast
// grid (252, 10), block 256
// ---------------------------------------------------------------------------
__global__ __launch_bounds__(256)
void prep_weights(const float* __restrict__ w0, const float* __restrict__ w1,
                  const float* __restrict__ w2, const float* __restrict__ w3,
                  const float* __restrict__ w4, unsigned short* __restrict__ dst,
                  const float* __restrict__ v0, const float* __restrict__ v1,
                  const float* __restrict__ v2, const float* __restrict__ v3,
                  const float* __restrict__ v4, unsigned short* __restrict__ dst1)
{
    int z = blockIdx.y;
    int i = blockIdx.x * 256 + threadIdx.x;
    if (z < 5) {
        const float* src; unsigned short* d; int C_out, COP;
        if (z < 3) {
            COP = 64; C_out = 64;
            src = (z == 0) ? w0 : (z == 1 ? w1 : w2);
            d = dst + z * 36864;
            if (i >= 36864) return;
        } else {
            COP = 112; C_out = 100;
            src = (z == 3) ? w3 : w4;
            d = dst + 110592 + (z - 3) * 64512;
            if (i >= 64512) return;
        }
        int tap = i / (COP * 64);
        int rem = i - tap * (COP * 64);
        int co = rem >> 6, ci = rem & 63;
        float v = (co < C_out) ? src[((size_t)co * 64 + ci) * 9 + tap] : 0.f;
        d[i] = f2bf(v);
    } else {
        int zz = z - 5;
        const float* s; int n; int off;
        if (zz == 0)      { s = v0; n = 8192;  off = 0; }
        else if (zz == 1) { s = v1; n = 16384; off = 8192; }
        else if (zz == 2) { s = v2; n = 32768; off = 24576; }
        else if (zz == 3) { s = v3; n = 4096;  off = 57344; }
        else              { s = v4; n = 4096;  off = 61440; }
        if (i >= n) return;
        dst1[off + i] = f2bf(s[i]);
    }
}

// ---------------------------------------------------------------------------
// conv3x3 body (bf16 MFMA 16x16x32, C_in=64, fp32 acc).  LDS 20736 B.
// R16: split-K staging (32 ch at a time), persistent accumulators.
// R18: PACKED variant — input is a bf16 channel-pair-packed mirror
// [b][cp=32][H][W] u32, written by OUR producers. Staging = 1 dword load +
// 1 LDS write per pair (was 2 fp32 loads + f2bf pack).  CPB stays 1
// (R1/R2 VGPR cliff).
// ---------------------------------------------------------------------------
template<int COP, int CSPLIT, int MODE, bool PACKED>
__device__ __forceinline__
void conv3x3_body(int rem, int TX, unsigned short* xs,
                  const float* __restrict__ x, const unsigned* __restrict__ xp,
                  const unsigned short* __restrict__ wt,
                  const float* __restrict__ p0, const float* __restrict__ p1,
                  const float* __restrict__ p2, const float* __restrict__ p3,
                  float* __restrict__ out, int H, int W, int C_out)
{
    constexpr int NP = 324;
    constexpr int CT = COP / 16;
    static_assert(CT == CSPLIT, "CPB must be 1 (R1/R2 VGPR cliff)");

    int cs = rem % CSPLIT;
    int b  = (rem / CSPLIT) & 3;
    int t  = rem / (CSPLIT * 4);
    int x0 = (t % TX) * 16, y0 = (t / TX) * 16;

    int tid  = threadIdx.x;
    int lane = tid & 63, wid = tid >> 6;
    int lrow = lane >> 4, lcol = lane & 15;
    int HWp = H * W;

    int co0 = cs * 16;
    bool colok = (x0 + lcol) < W;

    f32x4 accA[2], accB[2];
#pragma unroll
    for (int rr = 0; rr < 2; ++rr) {
        accA[rr] = (f32x4){0.f, 0.f, 0.f, 0.f};
        accB[rr] = (f32x4){0.f, 0.f, 0.f, 0.f};
    }

    unsigned int* wsl = (unsigned int*)xs;

#pragma unroll 1
    for (int kb = 0; kb < 2; ++kb) {
        if (kb) __syncthreads();          // protect xs before overwrite
        // ---- stage channels [kb*32, kb*32+32) of the 18x18 halo tile ----
        for (int p = tid; p < NP; p += 256) {
            int py = p / 18, px = p - py * 18;
            int gy = y0 + py - 1, gx = x0 + px - 1;
            bool ok = (gy >= 0) && (gy < H) && (gx >= 0) && (gx < W);
            if (PACKED) {
                const unsigned* gpp = xp + ((size_t)b * 32 + kb * 16) * HWp
                                         + (size_t)gy * W + gx;
#pragma unroll 8
                for (int cp = 0; cp < 16; ++cp) {
                    unsigned pk = ok ? gpp[(size_t)cp * HWp] : 0u;
                    wsl[((cp >> 2) * NP + p) * 4 + (cp & 3)] = pk;
                }
            } else {
                const float* gp = x + ((size_t)b * 64 + kb * 32) * HWp
                                    + (size_t)gy * W + gx;
#pragma unroll 8
                for (int cp = 0; cp < 16; ++cp) {
                    float v0 = 0.f, v1 = 0.f;
                    if (ok) {
                        v0 = gp[(size_t)(2 * cp) * HWp];
                        v1 = gp[(size_t)(2 * cp + 1) * HWp];
                    }
                    wsl[((cp >> 2) * NP + p) * 4 + (cp & 3)] = packbf(v0, v1);
                }
            }
        }
        __syncthreads();

        // ---- weights for this K-half: 9 taps x 1 frag ----
        bf16x8 a[9];
        const unsigned short* wl = wt + ((size_t)co0 + lcol) * 64 + kb * 32 + lrow * 8;
#pragma unroll
        for (int t9 = 0; t9 < 9; ++t9)
            a[t9] = *(const bf16x8*)(wl + (size_t)t9 * COP * 64);

        // ---- 18 MFMAs into persistent accumulators ----
#pragma unroll
        for (int rr = 0; rr < 2; ++rr) {
            int r0 = wid + rr * 8;
#pragma unroll
            for (int t9 = 0; t9 < 9; ++t9) {
                int dy = t9 / 3, dx = t9 - dy * 3;
                int g0 = lrow * NP + (r0 + dy) * 18 + lcol + dx;
                bf16x8 b0 = *(const bf16x8*)(xs + (size_t)g0 * 8);
                accA[rr] = __builtin_amdgcn_mfma_f32_16x16x32_bf16(a[t9], b0, accA[rr], 0, 0, 0);
                bf16x8 b1 = *(const bf16x8*)(xs + ((size_t)g0 + 4 * 18) * 8);
                accB[rr] = __builtin_amdgcn_mfma_f32_16x16x32_bf16(a[t9], b1, accB[rr], 0, 0, 0);
            }
        }
    }

    // ---- epilogue: BN/bias + store ----
    float sc[4], sh[4];
#pragma unroll
    for (int rg = 0; rg < 4; ++rg) {
        int co = co0 + lrow * 4 + rg;
        int cc = (co < C_out) ? co : 0;
        if (MODE == 0) { sc[rg] = 1.f; sh[rg] = p0[cc]; }
        else {
            float inv = p0[cc] * rsqrtf(p3[cc] + BN_EPS);
            sc[rg] = inv; sh[rg] = p1[cc] - p2[cc] * inv;
        }
    }
#pragma unroll
    for (int rr = 0; rr < 2; ++rr) {
        int r0 = wid + rr * 8;
        int yA = y0 + r0, yB = y0 + r0 + 4;
#pragma unroll
        for (int rg = 0; rg < 4; ++rg) {
            int co = co0 + lrow * 4 + rg;
            if (colok && co < C_out) {
                float* oc = out + (((size_t)b * C_out + co) * H) * W + x0 + lcol;
                if (yA < H) oc[(size_t)yA * W] = accA[rr][rg] * sc[rg] + sh[rg];
                if (yB < H) oc[(size_t)yB * W] = accB[rr][rg] * sc[rg] + sh[rg];
            }
        }
    }
}

// standalone conv3x3 (enc layers, fp32 input), grid (TX, TY, B*CSPLIT)
template<int COP, int CSPLIT, int MODE>
__global__ __launch_bounds__(256, 6)
void conv3x3_mfma(const float* __restrict__ x, const unsigned short* __restrict__ wt,
                  const float* __restrict__ p0, const float* __restrict__ p1,
                  const float* __restrict__ p2, const float* __restrict__ p3,
                  float* __restrict__ out, int H, int W, int C_out)
{
    __shared__ unsigned short xs[4 * 324 * 8];
    int TX = gridDim.x;
    int cs = blockIdx.z % CSPLIT;
    int b  = blockIdx.z / CSPLIT;
    int flat = (((blockIdx.y * TX + blockIdx.x) * 4 + b) * CSPLIT) + cs;
    conv3x3_body<COP, CSPLIT, MODE, false>(flat, TX, xs, x, nullptr, wt,
                                           p0, p1, p2, p3, out, H, W, C_out);
}

// fused fpn: SINGLE <64,4,0> instantiation, PACKED bf16-mirror inputs.
// level0: [0,960)  level1: [960,1200)  level2: [1200,1296).  grid (1296)
__global__ __launch_bounds__(256, 6)
void fpn_multi(const unsigned* __restrict__ l0p, const unsigned short* __restrict__ wt0,
               const float* __restrict__ b0, float* __restrict__ o0,
               const unsigned* __restrict__ l1p, const unsigned short* __restrict__ wt1,
               const float* __restrict__ b1, float* __restrict__ o1,
               const unsigned* __restrict__ l2p, const unsigned short* __restrict__ wt2,
               const float* __restrict__ b2, float* __restrict__ o2)
{
    __shared__ unsigned short xs[4 * 324 * 8];
    int f = blockIdx.x;
    const unsigned* xp; const unsigned short* wt; const float* bias; float* o;
    int H, W, TX, rem;
    if (f < 960)       { xp = l0p; wt = wt0; bias = b0; o = o0; H = 96; W = 160; TX = 10; rem = f; }
    else if (f < 1200) { xp = l1p; wt = wt1; bias = b1; o = o1; H = 48; W = 80;  TX = 5;  rem = f - 960; }
    else               { xp = l2p; wt = wt2; bias = b2; o = o2; H = 24; W = 40;  TX = 3;  rem = f - 1200; }
    conv3x3_body<64, 4, 0, true>(rem, TX, xs, nullptr, xp, wt,
                                 bias, nullptr, nullptr, nullptr, o, H, W, 64);
}

// ---------------------------------------------------------------------------
// conv1x1 body (bf16 MFMA GEMM).  xs = 4*NPX*8 shorts of LDS.
// ---------------------------------------------------------------------------
template<int C_IN, int KSPLIT, int NPX, int MODE>
__device__ __forceinline__
void conv1x1_body(int f, unsigned short* xs,
                  const float* __restrict__ x, const unsigned short* __restrict__ wb,
                  const float* __restrict__ p0, const float* __restrict__ p1,
                  const float* __restrict__ p2, const float* __restrict__ p3,
                  float* __restrict__ out, int HW)
{
    constexpr int NT = NPX / 16;
    constexpr int KLEN = C_IN / KSPLIT;
    int nb = HW / NPX;
    int px0 = (f % nb) * NPX;
    int ks  = (f / nb) % KSPLIT;
    int b   = f / (nb * KSPLIT);

    int tid = threadIdx.x;
    int lane = tid & 63, wid = tid >> 6;
    int lrow = lane >> 4, lcol = lane & 15;
    const float* xb = x + (size_t)b * C_IN * HW + px0;

    f32x4 acc[NT];
#pragma unroll
    for (int nt = 0; nt < NT; ++nt) acc[nt] = (f32x4){0.f, 0.f, 0.f, 0.f};

    for (int cc = 0; cc < KLEN; cc += 32) {
        if (cc) __syncthreads();
        int cb = ks * KLEN + cc;
#pragma unroll
        for (int t = 0; t < NPX / 16; ++t) {
            int i = tid + t * 256;
            int px = i & (NPX - 1);
            int cp = i / NPX;
            float v0 = xb[(size_t)(cb + 2 * cp) * HW + px];
            float v1 = xb[(size_t)(cb + 2 * cp + 1) * HW + px];
            ((unsigned*)xs)[((cp >> 2) * NPX + px) * 4 + (cp & 3)] = packbf(v0, v1);
        }
        __syncthreads();

        bf16x8 a = *(const bf16x8*)(wb + (size_t)(wid * 16 + lcol) * C_IN + cb + lrow * 8);
#pragma unroll
        for (int nt = 0; nt < NT; ++nt) {
            bf16x8 bf = *(const bf16x8*)(xs + ((size_t)lrow * NPX + nt * 16 + lcol) * 8);
            acc[nt] = __builtin_amdgcn_mfma_f32_16x16x32_bf16(a, bf, acc[nt], 0, 0, 0);
        }
    }

    if (KSPLIT == 1) {
#pragma unroll
        for (int rg = 0; rg < 4; ++rg) {
            int co = wid * 16 + lrow * 4 + rg;
            float scale, shift;
            if (MODE == 0) { scale = 1.f; shift = p0[co]; }
            else {
                float inv = p0[co] * rsqrtf(p3[co] + BN_EPS);
                scale = inv; shift = p1[co] - p2[co] * inv;
            }
            float* op = out + ((size_t)(b * 64 + co)) * HW + px0;
#pragma unroll
            for (int nt = 0; nt < NT; ++nt) {
                float r = acc[nt][rg] * scale + shift;
                if (MODE == 1) r = fmaxf(r, 0.f);
                op[nt * 16 + lcol] = r;
            }
        }
    } else {
#pragma unroll
        for (int rg = 0; rg < 4; ++rg) {
            int co = wid * 16 + lrow * 4 + rg;
            float* op = out + (((size_t)(ks * 4 + b)) * 64 + co) * HW + px0;
#pragma unroll
            for (int nt = 0; nt < NT; ++nt)
                op[nt * 16 + lcol] = acc[nt][rg];
        }
    }
}

// standalone conv1x1 (comp layers), grid (HW/NPX, 1, B)
template<int C_IN, int KSPLIT, int NPX, int MODE>
__global__ __launch_bounds__(256, 4)
void conv1x1_mfma(const float* __restrict__ x, const unsigned short* __restrict__ wb,
                  const float* __restrict__ p0, const float* __restrict__ p1,
                  const float* __restrict__ p2, const float* __restrict__ p3,
                  float* __restrict__ out, int HW)
{
    __shared__ __align__(16) unsigned short xs[4 * NPX * 8];
    int nb = HW / NPX;
    int f = blockIdx.x + nb * (blockIdx.y + KSPLIT * blockIdx.z);
    conv1x1_body<C_IN, KSPLIT, NPX, MODE>(f, xs, x, wb, p0, p1, p2, p3, out, HW);
}

// fused lateral convs: lat0 [0,480), lat1->part [480,720), lat2->part [720,960)
__global__ __launch_bounds__(256, 4)
void lat_multi(const float* __restrict__ x0, const unsigned short* __restrict__ w0,
               const float* __restrict__ b0, float* __restrict__ lat0,
               const float* __restrict__ x1, const unsigned short* __restrict__ w1,
               float* __restrict__ part1,
               const float* __restrict__ x2, const unsigned short* __restrict__ w2,
               float* __restrict__ part2)
{
    __shared__ __align__(16) unsigned short xs[4 * 128 * 8];
    int f = blockIdx.x;
    if (f < 480)
        conv1x1_body<128, 1, 128, 0>(f, xs, x0, w0, b0, nullptr, nullptr, nullptr, lat0, 15360);
    else if (f < 720)
        conv1x1_body<256, 2, 128, 0>(f - 480, xs, x1, w1, nullptr, nullptr, nullptr, nullptr, part1, 3840);
    else
        conv1x1_body<512, 4, 64, 0>(f - 720, xs, x2, w2, nullptr, nullptr, nullptr, nullptr, part2, 960);
}

// ---------------------------------------------------------------------------
// K-split reduce + bias.  lat1: plain fp32 (f in [0,960)).
// lat2: fp32 + bf16 pair-packed mirror (f in [960,1080); 30720 pair-float4s).
// ---------------------------------------------------------------------------
template<int KSPLIT>
__device__ __forceinline__
void reduce_body(int f, const float* __restrict__ part, const float* __restrict__ bias,
                 float* __restrict__ out, int HW, int N4)
{
    int i = f * 256 + threadIdx.x;
    if (i >= N4) return;
    size_t base = (size_t)i * 4;
    int co = (int)((base / (size_t)HW) & 63);
    size_t stride = (size_t)HW << 8;
    float4 s = *(const float4*)(part + base);
#pragma unroll
    for (int ks = 1; ks < KSPLIT; ++ks) {
        float4 t = *(const float4*)(part + (size_t)ks * stride + base);
        s.x += t.x; s.y += t.y; s.z += t.z; s.w += t.w;
    }
    float bv = bias[co];
    s.x += bv; s.y += bv; s.z += bv; s.w += bv;
    *(float4*)(out + base) = s;
}

__device__ __forceinline__
void reduce_pack4(int f, const float* __restrict__ part, const float* __restrict__ bias,
                  float* __restrict__ out, unsigned* __restrict__ outp, int HW, int N)
{
    int i = f * 256 + threadIdx.x;
    if (i >= N) return;                    // N = 4b * 32cp * (HW/4)
    int q = HW >> 2;
    int pxq  = i % q;
    int rest = i / q;                      // b*32 + cp
    int cp = rest & 31, b = rest >> 5;
    size_t off = (size_t)pxq * 4;
    size_t c0 = ((size_t)(b * 64 + 2 * cp)) * HW + off;
    size_t stride = (size_t)HW << 8;
    float4 s0 = *(const float4*)(part + c0);
    float4 s1 = *(const float4*)(part + c0 + HW);
#pragma unroll
    for (int ks = 1; ks < 4; ++ks) {
        float4 t0 = *(const float4*)(part + (size_t)ks * stride + c0);
        float4 t1 = *(const float4*)(part + (size_t)ks * stride + c0 + HW);
        s0.x += t0.x; s0.y += t0.y; s0.z += t0.z; s0.w += t0.w;
        s1.x += t1.x; s1.y += t1.y; s1.z += t1.z; s1.w += t1.w;
    }
    float bv0 = bias[2 * cp], bv1 = bias[2 * cp + 1];
    s0.x += bv0; s0.y += bv0; s0.z += bv0; s0.w += bv0;
    s1.x += bv1; s1.y += bv1; s1.z += bv1; s1.w += bv1;
    *(float4*)(out + c0) = s0;
    *(float4*)(out + c0 + HW) = s1;
    uint4 pk;
    pk.x = packbf(s0.x, s1.x);
    pk.y = packbf(s0.y, s1.y);
    pk.z = packbf(s0.z, s1.z);
    pk.w = packbf(s0.w, s1.w);
    *(uint4*)(outp + ((size_t)(b * 32 + cp)) * HW + off) = pk;
}

__global__ __launch_bounds__(256)
void reduce_multi(const float* __restrict__ part1, const float* __restrict__ b1,
                  float* __restrict__ lat1,
                  const float* __restrict__ part2, const float* __restrict__ b2,
                  float* __restrict__ lat2, unsigned* __restrict__ lat2p)
{
    int f = blockIdx.x;
    if (f < 960) reduce_body<2>(f, part1, b1, lat1, 3840, 245760);
    else         reduce_pack4(f - 960, part2, b2, lat2, lat2p, 960, 30720);
}

// ---------------------------------------------------------------------------
// CARAFE v5: channel-group split + bf16 mirror write.
// WF32: also write fp32 dst (needed when dst has downstream fp32 readers).
// u0 (dst=lat0): WF32=false — fpn0 reads only the mirror; saves 15.7 MB.
// bounds back to 4 (R17's 6 risked spills at ~80 live VGPR — R4 regression).
// grid: (2w/16, 2h/16, B * CGS), block 256
// ---------------------------------------------------------------------------
template<int CGS, bool WF32>
__global__ __launch_bounds__(256, 4)
void carafe_kernel(const float* __restrict__ src, const float* __restrict__ logits,
                   float* __restrict__ dst, unsigned* __restrict__ dstp, int h, int w)
{
    constexpr int SW = 12, NPX = 144;
    constexpr int CH = 64 / CGS;
    constexpr int CS = CH + 4;
    __shared__ float ls[NPX * CS];

    int tid = threadIdx.x;
    int x0 = blockIdx.x * 16, y0 = blockIdx.y * 16;
    int b  = blockIdx.z / CGS;
    int cs = blockIdx.z % CGS;
    int H = 2 * h, W = 2 * w;
    int xs0 = (x0 >> 1) - 2, ys0 = (y0 >> 1) - 2;
    size_t hw = (size_t)h * w;
    const float* sb = src + ((size_t)(b * 64 + cs * CH)) * hw;

    for (int i = tid; i < NPX * CH; i += 256) {
        int c = i / NPX, p = i - c * NPX;
        int yy = p / SW, xx = p - yy * SW;
        int sy = ys0 + yy, sx = xs0 + xx;
        float v = 0.f;
        if (sy >= 0 && sy < h && sx >= 0 && sx < w)
            v = sb[(size_t)c * hw + (size_t)sy * w + sx];
        ls[p * CS + c] = v;
    }
    __syncthreads();

    int lx = tid & 15, ty = tid >> 4;
    int x = x0 + lx, y = y0 + ty;
    int xw = x >> 1, yh = y >> 1;
    int par = (y & 1) * 2 + (x & 1);

    const float* lp = logits + ((size_t)(b * 100 + par) * h + yh) * w + xw;
    float l[25];
    float mx = -1e30f;
#pragma unroll
    for (int k = 0; k < 25; ++k) {
        l[k] = lp[(size_t)(4 * k) * hw];
        mx = fmaxf(mx, l[k]);
    }
    float s = 0.f;
#pragma unroll
    for (int k = 0; k < 25; ++k) {
        l[k] = __expf(l[k] - mx);
        s += l[k];
    }
    float invs = 1.f / s;
#pragma unroll
    for (int k = 0; k < 25; ++k) l[k] *= invs;

    int pb = (yh - ys0 - 2) * SW + (xw - xs0 - 2);

#pragma unroll 1
    for (int cg = 0; cg < CH / 16; ++cg) {
        float acc[16];
#pragma unroll
        for (int c = 0; c < 16; ++c) acc[c] = 0.f;
#pragma unroll
        for (int k = 0; k < 25; ++k) {
            int ti = k / 5, tj = k - ti * 5;
            const float* q = &ls[(pb + ti * SW + tj) * CS + cg * 16];
            float wk = l[k];
#pragma unroll
            for (int c = 0; c < 16; ++c)
                acc[c] = fmaf(wk, q[c], acc[c]);
        }
        int cbase = cs * CH + cg * 16;
        float* dp = dst + (((size_t)(b * 64 + cbase)) * H + y) * W + x;
        unsigned* pp = dstp + (((size_t)(b * 32 + (cbase >> 1))) * H + y) * W + x;
#pragma unroll
        for (int c = 0; c < 16; c += 2) {
            float n0 = dp[(size_t)c * H * W] + acc[c];
            float n1 = dp[(size_t)(c + 1) * H * W] + acc[c + 1];
            if (WF32) {
                dp[(size_t)c * H * W] = n0;
                dp[(size_t)(c + 1) * H * W] = n1;
            }
            pp[(size_t)(c >> 1) * H * W] = packbf(n0, n1);
        }
    }
}

// ---------------------------------------------------------------------------
extern "C" void kernel_launch(void* const* d_in, const int* in_sizes, int n_in,
                              void* d_out, int out_size, void* d_ws, size_t ws_size,
                              hipStream_t stream)
{
    const float* x0      = (const float*)d_in[0];
    const float* lat0_w  = (const float*)d_in[1];
    const float* lat0_b  = (const float*)d_in[2];
    const float* fpn0_w  = (const float*)d_in[3];
    const float* fpn0_b  = (const float*)d_in[4];
    const float* x1      = (const float*)d_in[5];
    const float* lat1_w  = (const float*)d_in[6];
    const float* lat1_b  = (const float*)d_in[7];
    const float* fpn1_w  = (const float*)d_in[8];
    const float* fpn1_b  = (const float*)d_in[9];
    const float* x2      = (const float*)d_in[10];
    const float* lat2_w  = (const float*)d_in[11];
    const float* lat2_b  = (const float*)d_in[12];
    const float* fpn2_w  = (const float*)d_in[13];
    const float* fpn2_b  = (const float*)d_in[14];
    const float* u0_comp_w = (const float*)d_in[15];
    const float* u0_enc_w  = (const float*)d_in[16];
    const float* u0_comp_g  = (const float*)d_in[17];
    const float* u0_comp_bt = (const float*)d_in[18];
    const float* u0_comp_m  = (const float*)d_in[19];
    const float* u0_comp_v  = (const float*)d_in[20];
    const float* u0_enc_g   = (const float*)d_in[21];
    const float* u0_enc_bt  = (const float*)d_in[22];
    const float* u0_enc_m   = (const float*)d_in[23];
    const float* u0_enc_v   = (const float*)d_in[24];
    const float* u1_comp_w = (const float*)d_in[25];
    const float* u1_enc_w  = (const float*)d_in[26];
    const float* u1_comp_g  = (const float*)d_in[27];
    const float* u1_comp_bt = (const float*)d_in[28];
    const float* u1_comp_m  = (const float*)d_in[29];
    const float* u1_comp_v  = (const float*)d_in[30];
    const float* u1_enc_g   = (const float*)d_in[31];
    const float* u1_enc_bt  = (const float*)d_in[32];
    const float* u1_enc_m   = (const float*)d_in[33];
    const float* u1_enc_v   = (const float*)d_in[34];

    float* out = (float*)d_out;
    const size_t OUT0 = 4ull * 64 * 96 * 160;   // 3,932,160
    const size_t OUT1 = 4ull * 64 * 48 * 80;    //   983,040
    const size_t OUT2 = 4ull * 64 * 24 * 40;    //   245,760
    float* out0 = out;
    float* out1 = out + OUT0;
    float* out2 = out + OUT0 + OUT1;

    float* lat0 = (float*)d_ws;
    float* lat1 = lat0 + OUT0;
    float* lat2 = lat1 + OUT1;
    unsigned short* wtb = (unsigned short*)(lat2 + OUT2);   // 239,616 bf16
    unsigned short* wt_fpn0 = wtb;
    unsigned short* wt_fpn1 = wtb + 36864;
    unsigned short* wt_fpn2 = wtb + 73728;
    unsigned short* wt_enc0 = wtb + 110592;
    unsigned short* wt_enc1 = wtb + 175104;
    unsigned short* wb = wtb + 239616;                      // 65,536 bf16 (1x1)
    unsigned short* wb_lat0  = wb;
    unsigned short* wb_lat1  = wb + 8192;
    unsigned short* wb_lat2  = wb + 24576;
    unsigned short* wb_comp0 = wb + 57344;
    unsigned short* wb_comp1 = wb + 61440;
    // bf16 channel-pair-packed mirrors ([b][cp=32][H][W] u32):
    unsigned* lat0p = (unsigned*)(wb + 65536);              // 1,966,080 u32
    unsigned* lat1p = lat0p + 1966080;                      //   491,520 u32
    unsigned* lat2p = lat1p + 491520;                       //   122,880 u32
    // out0 region doubles as scratch (fpn_multi overwrites it LAST):
    float* part1 = out0;                 // lat1 partials: 2*983,040
    float* part2 = out0 + 2 * OUT1;      // lat2 partials: 4*245,760
    float* comp  = out0;                 // comp logits (after reduces consume parts)
    float* enc   = out0 + OUT1;          // enc logits

    dim3 blk(256);

    // 0) weight prep
    prep_weights<<<dim3(252, 10), blk, 0, stream>>>(
        fpn0_w, fpn1_w, fpn2_w, u0_enc_w, u1_enc_w, wtb,
        lat0_w, lat1_w, lat2_w, u0_comp_w, u1_comp_w, wb);

    // 1) all three lateral 1x1 convs — ONE dispatch (960 blocks)
    lat_multi<<<dim3(960), blk, 0, stream>>>(
        x0, wb_lat0, lat0_b, lat0, x1, wb_lat1, part1, x2, wb_lat2, part2);

    // 2) both K-split reduces (lat2 also emits bf16 mirror) — ONE dispatch
    reduce_multi<<<dim3(1080), blk, 0, stream>>>(
        part1, lat1_b, lat1, part2, lat2_b, lat2, lat2p);

    // 3) CARAFE u1: lat1 += carafe(lat2)   (writes fp32 + mirror)
    conv1x1_mfma<64, 1, 32, 1><<<dim3(30, 1, 4), blk, 0, stream>>>(
        lat2, wb_comp1, u1_comp_g, u1_comp_bt, u1_comp_m, u1_comp_v, comp, 24 * 40);
    conv3x3_mfma<112, 7, 1><<<dim3(3, 2, 28), blk, 0, stream>>>(
        comp, wt_enc1, u1_enc_g, u1_enc_bt, u1_enc_m, u1_enc_v, enc, 24, 40, 100);
    carafe_kernel<2, true><<<dim3(5, 3, 8), blk, 0, stream>>>(lat2, enc, lat1, lat1p, 24, 40);

    // 4) CARAFE u0: lat0 += carafe(lat1)   (mirror only — fpn0 is sole reader)
    conv1x1_mfma<64, 1, 128, 1><<<dim3(30, 1, 4), blk, 0, stream>>>(
        lat1, wb_comp0, u0_comp_g, u0_comp_bt, u0_comp_m, u0_comp_v, comp, 48 * 80);
    conv3x3_mfma<112, 7, 1><<<dim3(5, 3, 28), blk, 0, stream>>>(
        comp, wt_enc0, u0_enc_g, u0_enc_bt, u0_enc_m, u0_enc_v, enc, 48, 80, 100);
    carafe_kernel<2, false><<<dim3(10, 6, 8), blk, 0, stream>>>(lat1, enc, lat0, lat0p, 48, 80);

    // 5) all three output 3x3 convs — ONE dispatch, PACKED mirror inputs
    fpn_multi<<<dim3(1296), blk, 0, stream>>>(
        lat0p, wt_fpn0, fpn0_b, out0,
        lat1p, wt_fpn1, fpn1_b, out1,
        lat2p, wt_fpn2, fpn2_b, out2);
}

// Round 6
// 322.544 us; speedup vs baseline: 1.0829x; 1.0144x over previous
//
#include <hip/hip_runtime.h>

#define BN_EPS 1e-5f

typedef __attribute__((ext_vector_type(8))) short bf16x8;
typedef __attribute__((ext_vector_type(4))) float f32x4;

__device__ __forceinline__ unsigned short f2bf(float f) {
    unsigned u = __float_as_uint(f);
    return (unsigned short)((u + 0x7fffu + ((u >> 16) & 1u)) >> 16);   // RNE
}
__device__ __forceinline__ unsigned packbf(float lo, float hi) {
    return ((unsigned)f2bf(hi) << 16) | (unsigned)f2bf(lo);
}

// ---------------------------------------------------------------------------
// Weight prep (ONE launch): conv3x3 -> wt[tap][co][ci] bf16; 1x1 -> bf16 cast
// grid (252, 10), block 256
// ---------------------------------------------------------------------------
__global__ __launch_bounds__(256)
void prep_weights(const float* __restrict__ w0, const float* __restrict__ w1,
                  const float* __restrict__ w2, const float* __restrict__ w3,
                  const float* __restrict__ w4, unsigned short* __restrict__ dst,
                  const float* __restrict__ v0, const float* __restrict__ v1,
                  const float* __restrict__ v2, const float* __restrict__ v3,
                  const float* __restrict__ v4, unsigned short* __restrict__ dst1)
{
    int z = blockIdx.y;
    int i = blockIdx.x * 256 + threadIdx.x;
    if (z < 5) {
        const float* src; unsigned short* d; int C_out, COP;
        if (z < 3) {
            COP = 64; C_out = 64;
            src = (z == 0) ? w0 : (z == 1 ? w1 : w2);
            d = dst + z * 36864;
            if (i >= 36864) return;
        } else {
            COP = 112; C_out = 100;
            src = (z == 3) ? w3 : w4;
            d = dst + 110592 + (z - 3) * 64512;
            if (i >= 64512) return;
        }
        int tap = i / (COP * 64);
        int rem = i - tap * (COP * 64);
        int co = rem >> 6, ci = rem & 63;
        float v = (co < C_out) ? src[((size_t)co * 64 + ci) * 9 + tap] : 0.f;
        d[i] = f2bf(v);
    } else {
        int zz = z - 5;
        const float* s; int n; int off;
        if (zz == 0)      { s = v0; n = 8192;  off = 0; }
        else if (zz == 1) { s = v1; n = 16384; off = 8192; }
        else if (zz == 2) { s = v2; n = 32768; off = 24576; }
        else if (zz == 3) { s = v3; n = 4096;  off = 57344; }
        else              { s = v4; n = 4096;  off = 61440; }
        if (i >= n) return;
        dst1[off + i] = f2bf(s[i]);
    }
}

// ---------------------------------------------------------------------------
// conv3x3 body (bf16 MFMA 16x16x32, C_in=64, fp32 acc).  LDS 20736 B.
// R16: split-K staging (32 ch at a time), persistent accumulators.
// R18: PACKED variant — bf16 channel-pair-packed mirror input.
// CPB stays 1 (R1/R2 VGPR cliff).
// ---------------------------------------------------------------------------
template<int COP, int CSPLIT, int MODE, bool PACKED>
__device__ __forceinline__
void conv3x3_body(int rem, int TX, unsigned short* xs,
                  const float* __restrict__ x, const unsigned* __restrict__ xp,
                  const unsigned short* __restrict__ wt,
                  const float* __restrict__ p0, const float* __restrict__ p1,
                  const float* __restrict__ p2, const float* __restrict__ p3,
                  float* __restrict__ out, int H, int W, int C_out)
{
    constexpr int NP = 324;
    constexpr int CT = COP / 16;
    static_assert(CT == CSPLIT, "CPB must be 1 (R1/R2 VGPR cliff)");

    int cs = rem % CSPLIT;
    int b  = (rem / CSPLIT) & 3;
    int t  = rem / (CSPLIT * 4);
    int x0 = (t % TX) * 16, y0 = (t / TX) * 16;

    int tid  = threadIdx.x;
    int lane = tid & 63, wid = tid >> 6;
    int lrow = lane >> 4, lcol = lane & 15;
    int HWp = H * W;

    int co0 = cs * 16;
    bool colok = (x0 + lcol) < W;

    f32x4 accA[2], accB[2];
#pragma unroll
    for (int rr = 0; rr < 2; ++rr) {
        accA[rr] = (f32x4){0.f, 0.f, 0.f, 0.f};
        accB[rr] = (f32x4){0.f, 0.f, 0.f, 0.f};
    }

    unsigned int* wsl = (unsigned int*)xs;

#pragma unroll 1
    for (int kb = 0; kb < 2; ++kb) {
        if (kb) __syncthreads();          // protect xs before overwrite
        // ---- stage channels [kb*32, kb*32+32) of the 18x18 halo tile ----
        for (int p = tid; p < NP; p += 256) {
            int py = p / 18, px = p - py * 18;
            int gy = y0 + py - 1, gx = x0 + px - 1;
            bool ok = (gy >= 0) && (gy < H) && (gx >= 0) && (gx < W);
            if (PACKED) {
                const unsigned* gpp = xp + ((size_t)b * 32 + kb * 16) * HWp
                                         + (size_t)gy * W + gx;
#pragma unroll 8
                for (int cp = 0; cp < 16; ++cp) {
                    unsigned pk = ok ? gpp[(size_t)cp * HWp] : 0u;
                    wsl[((cp >> 2) * NP + p) * 4 + (cp & 3)] = pk;
                }
            } else {
                const float* gp = x + ((size_t)b * 64 + kb * 32) * HWp
                                    + (size_t)gy * W + gx;
#pragma unroll 8
                for (int cp = 0; cp < 16; ++cp) {
                    float v0 = 0.f, v1 = 0.f;
                    if (ok) {
                        v0 = gp[(size_t)(2 * cp) * HWp];
                        v1 = gp[(size_t)(2 * cp + 1) * HWp];
                    }
                    wsl[((cp >> 2) * NP + p) * 4 + (cp & 3)] = packbf(v0, v1);
                }
            }
        }
        __syncthreads();

        // ---- weights for this K-half: 9 taps x 1 frag ----
        bf16x8 a[9];
        const unsigned short* wl = wt + ((size_t)co0 + lcol) * 64 + kb * 32 + lrow * 8;
#pragma unroll
        for (int t9 = 0; t9 < 9; ++t9)
            a[t9] = *(const bf16x8*)(wl + (size_t)t9 * COP * 64);

        // ---- 18 MFMAs into persistent accumulators ----
#pragma unroll
        for (int rr = 0; rr < 2; ++rr) {
            int r0 = wid + rr * 8;
#pragma unroll
            for (int t9 = 0; t9 < 9; ++t9) {
                int dy = t9 / 3, dx = t9 - dy * 3;
                int g0 = lrow * NP + (r0 + dy) * 18 + lcol + dx;
                bf16x8 b0 = *(const bf16x8*)(xs + (size_t)g0 * 8);
                accA[rr] = __builtin_amdgcn_mfma_f32_16x16x32_bf16(a[t9], b0, accA[rr], 0, 0, 0);
                bf16x8 b1 = *(const bf16x8*)(xs + ((size_t)g0 + 4 * 18) * 8);
                accB[rr] = __builtin_amdgcn_mfma_f32_16x16x32_bf16(a[t9], b1, accB[rr], 0, 0, 0);
            }
        }
    }

    // ---- epilogue: BN/bias + store ----
    float sc[4], sh[4];
#pragma unroll
    for (int rg = 0; rg < 4; ++rg) {
        int co = co0 + lrow * 4 + rg;
        int cc = (co < C_out) ? co : 0;
        if (MODE == 0) { sc[rg] = 1.f; sh[rg] = p0[cc]; }
        else {
            float inv = p0[cc] * rsqrtf(p3[cc] + BN_EPS);
            sc[rg] = inv; sh[rg] = p1[cc] - p2[cc] * inv;
        }
    }
#pragma unroll
    for (int rr = 0; rr < 2; ++rr) {
        int r0 = wid + rr * 8;
        int yA = y0 + r0, yB = y0 + r0 + 4;
#pragma unroll
        for (int rg = 0; rg < 4; ++rg) {
            int co = co0 + lrow * 4 + rg;
            if (colok && co < C_out) {
                float* oc = out + (((size_t)b * C_out + co) * H) * W + x0 + lcol;
                if (yA < H) oc[(size_t)yA * W] = accA[rr][rg] * sc[rg] + sh[rg];
                if (yB < H) oc[(size_t)yB * W] = accB[rr][rg] * sc[rg] + sh[rg];
            }
        }
    }
}

// R19: enc conv3x3 + independent fpn level merged into ONE dispatch.
// Blocks [0,encBlocks) run the enc conv (<112,7,1>, fp32 input); blocks
// [encBlocks,..) run an fpn conv (<64,4,0>, packed input) whose inputs are
// already ready — backfills the idle CUs the small enc grids leave.
// Revert trigger: VGPR > ~64 (two instantiations share regalloc).
__global__ __launch_bounds__(256, 6)
void enc_fpn(int encBlocks,
             const float* __restrict__ cx, const unsigned short* __restrict__ wt_e,
             const float* __restrict__ g, const float* __restrict__ bt,
             const float* __restrict__ m, const float* __restrict__ v,
             float* __restrict__ enc_out, int He, int We, int TXe,
             const unsigned* __restrict__ xp, const unsigned short* __restrict__ wt_f,
             const float* __restrict__ bias, float* __restrict__ fout,
             int Hf, int Wf, int TXf)
{
    __shared__ unsigned short xs[4 * 324 * 8];
    int f = blockIdx.x;
    if (f < encBlocks)
        conv3x3_body<112, 7, 1, false>(f, TXe, xs, cx, nullptr, wt_e,
                                       g, bt, m, v, enc_out, He, We, 100);
    else
        conv3x3_body<64, 4, 0, true>(f - encBlocks, TXf, xs, nullptr, xp, wt_f,
                                     bias, nullptr, nullptr, nullptr, fout, Hf, Wf, 64);
}

// final fpn: level0 only (levels 1/2 backfilled into enc dispatches).
// grid (960)
__global__ __launch_bounds__(256, 6)
void fpn_multi(const unsigned* __restrict__ l0p, const unsigned short* __restrict__ wt0,
               const float* __restrict__ b0, float* __restrict__ o0)
{
    __shared__ unsigned short xs[4 * 324 * 8];
    conv3x3_body<64, 4, 0, true>(blockIdx.x, 10, xs, nullptr, l0p, wt0,
                                 b0, nullptr, nullptr, nullptr, o0, 96, 160, 64);
}

// ---------------------------------------------------------------------------
// conv1x1 body (bf16 MFMA GEMM).  xs = 4*NPX*8 shorts of LDS.
// ---------------------------------------------------------------------------
template<int C_IN, int KSPLIT, int NPX, int MODE>
__device__ __forceinline__
void conv1x1_body(int f, unsigned short* xs,
                  const float* __restrict__ x, const unsigned short* __restrict__ wb,
                  const float* __restrict__ p0, const float* __restrict__ p1,
                  const float* __restrict__ p2, const float* __restrict__ p3,
                  float* __restrict__ out, int HW)
{
    constexpr int NT = NPX / 16;
    constexpr int KLEN = C_IN / KSPLIT;
    int nb = HW / NPX;
    int px0 = (f % nb) * NPX;
    int ks  = (f / nb) % KSPLIT;
    int b   = f / (nb * KSPLIT);

    int tid = threadIdx.x;
    int lane = tid & 63, wid = tid >> 6;
    int lrow = lane >> 4, lcol = lane & 15;
    const float* xb = x + (size_t)b * C_IN * HW + px0;

    f32x4 acc[NT];
#pragma unroll
    for (int nt = 0; nt < NT; ++nt) acc[nt] = (f32x4){0.f, 0.f, 0.f, 0.f};

    for (int cc = 0; cc < KLEN; cc += 32) {
        if (cc) __syncthreads();
        int cb = ks * KLEN + cc;
#pragma unroll
        for (int t = 0; t < NPX / 16; ++t) {
            int i = tid + t * 256;
            int px = i & (NPX - 1);
            int cp = i / NPX;
            float v0 = xb[(size_t)(cb + 2 * cp) * HW + px];
            float v1 = xb[(size_t)(cb + 2 * cp + 1) * HW + px];
            ((unsigned*)xs)[((cp >> 2) * NPX + px) * 4 + (cp & 3)] = packbf(v0, v1);
        }
        __syncthreads();

        bf16x8 a = *(const bf16x8*)(wb + (size_t)(wid * 16 + lcol) * C_IN + cb + lrow * 8);
#pragma unroll
        for (int nt = 0; nt < NT; ++nt) {
            bf16x8 bf = *(const bf16x8*)(xs + ((size_t)lrow * NPX + nt * 16 + lcol) * 8);
            acc[nt] = __builtin_amdgcn_mfma_f32_16x16x32_bf16(a, bf, acc[nt], 0, 0, 0);
        }
    }

    if (KSPLIT == 1) {
#pragma unroll
        for (int rg = 0; rg < 4; ++rg) {
            int co = wid * 16 + lrow * 4 + rg;
            float scale, shift;
            if (MODE == 0) { scale = 1.f; shift = p0[co]; }
            else {
                float inv = p0[co] * rsqrtf(p3[co] + BN_EPS);
                scale = inv; shift = p1[co] - p2[co] * inv;
            }
            float* op = out + ((size_t)(b * 64 + co)) * HW + px0;
#pragma unroll
            for (int nt = 0; nt < NT; ++nt) {
                float r = acc[nt][rg] * scale + shift;
                if (MODE == 1) r = fmaxf(r, 0.f);
                op[nt * 16 + lcol] = r;
            }
        }
    } else {
#pragma unroll
        for (int rg = 0; rg < 4; ++rg) {
            int co = wid * 16 + lrow * 4 + rg;
            float* op = out + (((size_t)(ks * 4 + b)) * 64 + co) * HW + px0;
#pragma unroll
            for (int nt = 0; nt < NT; ++nt)
                op[nt * 16 + lcol] = acc[nt][rg];
        }
    }
}

// standalone conv1x1 (comp layers), grid (HW/NPX, 1, B)
template<int C_IN, int KSPLIT, int NPX, int MODE>
__global__ __launch_bounds__(256, 4)
void conv1x1_mfma(const float* __restrict__ x, const unsigned short* __restrict__ wb,
                  const float* __restrict__ p0, const float* __restrict__ p1,
                  const float* __restrict__ p2, const float* __restrict__ p3,
                  float* __restrict__ out, int HW)
{
    __shared__ __align__(16) unsigned short xs[4 * NPX * 8];
    int nb = HW / NPX;
    int f = blockIdx.x + nb * (blockIdx.y + KSPLIT * blockIdx.z);
    conv1x1_body<C_IN, KSPLIT, NPX, MODE>(f, xs, x, wb, p0, p1, p2, p3, out, HW);
}

// fused lateral convs: lat0 [0,480), lat1->part [480,720), lat2->part [720,960)
__global__ __launch_bounds__(256, 4)
void lat_multi(const float* __restrict__ x0, const unsigned short* __restrict__ w0,
               const float* __restrict__ b0, float* __restrict__ lat0,
               const float* __restrict__ x1, const unsigned short* __restrict__ w1,
               float* __restrict__ part1,
               const float* __restrict__ x2, const unsigned short* __restrict__ w2,
               float* __restrict__ part2)
{
    __shared__ __align__(16) unsigned short xs[4 * 128 * 8];
    int f = blockIdx.x;
    if (f < 480)
        conv1x1_body<128, 1, 128, 0>(f, xs, x0, w0, b0, nullptr, nullptr, nullptr, lat0, 15360);
    else if (f < 720)
        conv1x1_body<256, 2, 128, 0>(f - 480, xs, x1, w1, nullptr, nullptr, nullptr, nullptr, part1, 3840);
    else
        conv1x1_body<512, 4, 64, 0>(f - 720, xs, x2, w2, nullptr, nullptr, nullptr, nullptr, part2, 960);
}

// ---------------------------------------------------------------------------
// K-split reduce + bias.  lat1: plain fp32 (f in [0,960)).
// lat2: fp32 + bf16 pair-packed mirror (f in [960,1080)).
// ---------------------------------------------------------------------------
template<int KSPLIT>
__device__ __forceinline__
void reduce_body(int f, const float* __restrict__ part, const float* __restrict__ bias,
                 float* __restrict__ out, int HW, int N4)
{
    int i = f * 256 + threadIdx.x;
    if (i >= N4) return;
    size_t base = (size_t)i * 4;
    int co = (int)((base / (size_t)HW) & 63);
    size_t stride = (size_t)HW << 8;
    float4 s = *(const float4*)(part + base);
#pragma unroll
    for (int ks = 1; ks < KSPLIT; ++ks) {
        float4 t = *(const float4*)(part + (size_t)ks * stride + base);
        s.x += t.x; s.y += t.y; s.z += t.z; s.w += t.w;
    }
    float bv = bias[co];
    s.x += bv; s.y += bv; s.z += bv; s.w += bv;
    *(float4*)(out + base) = s;
}

__device__ __forceinline__
void reduce_pack4(int f, const float* __restrict__ part, const float* __restrict__ bias,
                  float* __restrict__ out, unsigned* __restrict__ outp, int HW, int N)
{
    int i = f * 256 + threadIdx.x;
    if (i >= N) return;                    // N = 4b * 32cp * (HW/4)
    int q = HW >> 2;
    int pxq  = i % q;
    int rest = i / q;                      // b*32 + cp
    int cp = rest & 31, b = rest >> 5;
    size_t off = (size_t)pxq * 4;
    size_t c0 = ((size_t)(b * 64 + 2 * cp)) * HW + off;
    size_t stride = (size_t)HW << 8;
    float4 s0 = *(const float4*)(part + c0);
    float4 s1 = *(const float4*)(part + c0 + HW);
#pragma unroll
    for (int ks = 1; ks < 4; ++ks) {
        float4 t0 = *(const float4*)(part + (size_t)ks * stride + c0);
        float4 t1 = *(const float4*)(part + (size_t)ks * stride + c0 + HW);
        s0.x += t0.x; s0.y += t0.y; s0.z += t0.z; s0.w += t0.w;
        s1.x += t1.x; s1.y += t1.y; s1.z += t1.z; s1.w += t1.w;
    }
    float bv0 = bias[2 * cp], bv1 = bias[2 * cp + 1];
    s0.x += bv0; s0.y += bv0; s0.z += bv0; s0.w += bv0;
    s1.x += bv1; s1.y += bv1; s1.z += bv1; s1.w += bv1;
    *(float4*)(out + c0) = s0;
    *(float4*)(out + c0 + HW) = s1;
    uint4 pk;
    pk.x = packbf(s0.x, s1.x);
    pk.y = packbf(s0.y, s1.y);
    pk.z = packbf(s0.z, s1.z);
    pk.w = packbf(s0.w, s1.w);
    *(uint4*)(outp + ((size_t)(b * 32 + cp)) * HW + off) = pk;
}

__global__ __launch_bounds__(256)
void reduce_multi(const float* __restrict__ part1, const float* __restrict__ b1,
                  float* __restrict__ lat1,
                  const float* __restrict__ part2, const float* __restrict__ b2,
                  float* __restrict__ lat2, unsigned* __restrict__ lat2p)
{
    int f = blockIdx.x;
    if (f < 960) reduce_body<2>(f, part1, b1, lat1, 3840, 245760);
    else         reduce_pack4(f - 960, part2, b2, lat2, lat2p, 960, 30720);
}

// ---------------------------------------------------------------------------
// CARAFE v5: channel-group split + bf16 mirror write.
// WF32: also write fp32 dst.  u0 (dst=lat0): WF32=false — fpn0 reads only the
// mirror; saves 15.7 MB.  bounds 4 (R4: 6 regressed, ~80 live VGPR).
// grid: (2w/16, 2h/16, B * CGS), block 256
// ---------------------------------------------------------------------------
template<int CGS, bool WF32>
__global__ __launch_bounds__(256, 4)
void carafe_kernel(const float* __restrict__ src, const float* __restrict__ logits,
                   float* __restrict__ dst, unsigned* __restrict__ dstp, int h, int w)
{
    constexpr int SW = 12, NPX = 144;
    constexpr int CH = 64 / CGS;
    constexpr int CS = CH + 4;
    __shared__ float ls[NPX * CS];

    int tid = threadIdx.x;
    int x0 = blockIdx.x * 16, y0 = blockIdx.y * 16;
    int b  = blockIdx.z / CGS;
    int cs = blockIdx.z % CGS;
    int H = 2 * h, W = 2 * w;
    int xs0 = (x0 >> 1) - 2, ys0 = (y0 >> 1) - 2;
    size_t hw = (size_t)h * w;
    const float* sb = src + ((size_t)(b * 64 + cs * CH)) * hw;

    for (int i = tid; i < NPX * CH; i += 256) {
        int c = i / NPX, p = i - c * NPX;
        int yy = p / SW, xx = p - yy * SW;
        int sy = ys0 + yy, sx = xs0 + xx;
        float v = 0.f;
        if (sy >= 0 && sy < h && sx >= 0 && sx < w)
            v = sb[(size_t)c * hw + (size_t)sy * w + sx];
        ls[p * CS + c] = v;
    }
    __syncthreads();

    int lx = tid & 15, ty = tid >> 4;
    int x = x0 + lx, y = y0 + ty;
    int xw = x >> 1, yh = y >> 1;
    int par = (y & 1) * 2 + (x & 1);

    const float* lp = logits + ((size_t)(b * 100 + par) * h + yh) * w + xw;
    float l[25];
    float mx = -1e30f;
#pragma unroll
    for (int k = 0; k < 25; ++k) {
        l[k] = lp[(size_t)(4 * k) * hw];
        mx = fmaxf(mx, l[k]);
    }
    float s = 0.f;
#pragma unroll
    for (int k = 0; k < 25; ++k) {
        l[k] = __expf(l[k] - mx);
        s += l[k];
    }
    float invs = 1.f / s;
#pragma unroll
    for (int k = 0; k < 25; ++k) l[k] *= invs;

    int pb = (yh - ys0 - 2) * SW + (xw - xs0 - 2);

#pragma unroll 1
    for (int cg = 0; cg < CH / 16; ++cg) {
        float acc[16];
#pragma unroll
        for (int c = 0; c < 16; ++c) acc[c] = 0.f;
#pragma unroll
        for (int k = 0; k < 25; ++k) {
            int ti = k / 5, tj = k - ti * 5;
            const float* q = &ls[(pb + ti * SW + tj) * CS + cg * 16];
            float wk = l[k];
#pragma unroll
            for (int c = 0; c < 16; ++c)
                acc[c] = fmaf(wk, q[c], acc[c]);
        }
        int cbase = cs * CH + cg * 16;
        float* dp = dst + (((size_t)(b * 64 + cbase)) * H + y) * W + x;
        unsigned* pp = dstp + (((size_t)(b * 32 + (cbase >> 1))) * H + y) * W + x;
#pragma unroll
        for (int c = 0; c < 16; c += 2) {
            float n0 = dp[(size_t)c * H * W] + acc[c];
            float n1 = dp[(size_t)(c + 1) * H * W] + acc[c + 1];
            if (WF32) {
                dp[(size_t)c * H * W] = n0;
                dp[(size_t)(c + 1) * H * W] = n1;
            }
            pp[(size_t)(c >> 1) * H * W] = packbf(n0, n1);
        }
    }
}

// ---------------------------------------------------------------------------
extern "C" void kernel_launch(void* const* d_in, const int* in_sizes, int n_in,
                              void* d_out, int out_size, void* d_ws, size_t ws_size,
                              hipStream_t stream)
{
    const float* x0      = (const float*)d_in[0];
    const float* lat0_w  = (const float*)d_in[1];
    const float* lat0_b  = (const float*)d_in[2];
    const float* fpn0_w  = (const float*)d_in[3];
    const float* fpn0_b  = (const float*)d_in[4];
    const float* x1      = (const float*)d_in[5];
    const float* lat1_w  = (const float*)d_in[6];
    const float* lat1_b  = (const float*)d_in[7];
    const float* fpn1_w  = (const float*)d_in[8];
    const float* fpn1_b  = (const float*)d_in[9];
    const float* x2      = (const float*)d_in[10];
    const float* lat2_w  = (const float*)d_in[11];
    const float* lat2_b  = (const float*)d_in[12];
    const float* fpn2_w  = (const float*)d_in[13];
    const float* fpn2_b  = (const float*)d_in[14];
    const float* u0_comp_w = (const float*)d_in[15];
    const float* u0_enc_w  = (const float*)d_in[16];
    const float* u0_comp_g  = (const float*)d_in[17];
    const float* u0_comp_bt = (const float*)d_in[18];
    const float* u0_comp_m  = (const float*)d_in[19];
    const float* u0_comp_v  = (const float*)d_in[20];
    const float* u0_enc_g   = (const float*)d_in[21];
    const float* u0_enc_bt  = (const float*)d_in[22];
    const float* u0_enc_m   = (const float*)d_in[23];
    const float* u0_enc_v   = (const float*)d_in[24];
    const float* u1_comp_w = (const float*)d_in[25];
    const float* u1_enc_w  = (const float*)d_in[26];
    const float* u1_comp_g  = (const float*)d_in[27];
    const float* u1_comp_bt = (const float*)d_in[28];
    const float* u1_comp_m  = (const float*)d_in[29];
    const float* u1_comp_v  = (const float*)d_in[30];
    const float* u1_enc_g   = (const float*)d_in[31];
    const float* u1_enc_bt  = (const float*)d_in[32];
    const float* u1_enc_m   = (const float*)d_in[33];
    const float* u1_enc_v   = (const float*)d_in[34];

    float* out = (float*)d_out;
    const size_t OUT0 = 4ull * 64 * 96 * 160;   // 3,932,160
    const size_t OUT1 = 4ull * 64 * 48 * 80;    //   983,040
    const size_t OUT2 = 4ull * 64 * 24 * 40;    //   245,760
    float* out0 = out;
    float* out1 = out + OUT0;
    float* out2 = out + OUT0 + OUT1;

    float* lat0 = (float*)d_ws;
    float* lat1 = lat0 + OUT0;
    float* lat2 = lat1 + OUT1;
    unsigned short* wtb = (unsigned short*)(lat2 + OUT2);   // 239,616 bf16
    unsigned short* wt_fpn0 = wtb;
    unsigned short* wt_fpn1 = wtb + 36864;
    unsigned short* wt_fpn2 = wtb + 73728;
    unsigned short* wt_enc0 = wtb + 110592;
    unsigned short* wt_enc1 = wtb + 175104;
    unsigned short* wb = wtb + 239616;                      // 65,536 bf16 (1x1)
    unsigned short* wb_lat0  = wb;
    unsigned short* wb_lat1  = wb + 8192;
    unsigned short* wb_lat2  = wb + 24576;
    unsigned short* wb_comp0 = wb + 57344;
    unsigned short* wb_comp1 = wb + 61440;
    // bf16 channel-pair-packed mirrors ([b][cp=32][H][W] u32):
    unsigned* lat0p = (unsigned*)(wb + 65536);              // 1,966,080 u32
    unsigned* lat1p = lat0p + 1966080;                      //   491,520 u32
    unsigned* lat2p = lat1p + 491520;                       //   122,880 u32
    // out0 region doubles as scratch (fpn0 overwrites it LAST):
    float* part1 = out0;                 // lat1 partials: 2*983,040
    float* part2 = out0 + 2 * OUT1;      // lat2 partials: 4*245,760
    float* comp  = out0;                 // comp logits (after reduces consume parts)
    float* enc   = out0 + OUT1;          // enc logits

    dim3 blk(256);

    // 0) weight prep
    prep_weights<<<dim3(252, 10), blk, 0, stream>>>(
        fpn0_w, fpn1_w, fpn2_w, u0_enc_w, u1_enc_w, wtb,
        lat0_w, lat1_w, lat2_w, u0_comp_w, u1_comp_w, wb);

    // 1) all three lateral 1x1 convs — ONE dispatch (960 blocks)
    lat_multi<<<dim3(960), blk, 0, stream>>>(
        x0, wb_lat0, lat0_b, lat0, x1, wb_lat1, part1, x2, wb_lat2, part2);

    // 2) both K-split reduces (lat2 also emits bf16 mirror) — ONE dispatch
    reduce_multi<<<dim3(1080), blk, 0, stream>>>(
        part1, lat1_b, lat1, part2, lat2_b, lat2, lat2p);

    // 3) CARAFE u1: lat1 += carafe(lat2); fpn2 rides with enc1 (backfill)
    conv1x1_mfma<64, 1, 32, 1><<<dim3(30, 1, 4), blk, 0, stream>>>(
        lat2, wb_comp1, u1_comp_g, u1_comp_bt, u1_comp_m, u1_comp_v, comp, 24 * 40);
    enc_fpn<<<dim3(264), blk, 0, stream>>>(168,
        comp, wt_enc1, u1_enc_g, u1_enc_bt, u1_enc_m, u1_enc_v, enc, 24, 40, 3,
        lat2p, wt_fpn2, fpn2_b, out2, 24, 40, 3);
    carafe_kernel<2, true><<<dim3(5, 3, 8), blk, 0, stream>>>(lat2, enc, lat1, lat1p, 24, 40);

    // 4) CARAFE u0: lat0 += carafe(lat1); fpn1 rides with enc0 (backfill)
    conv1x1_mfma<64, 1, 128, 1><<<dim3(30, 1, 4), blk, 0, stream>>>(
        lat1, wb_comp0, u0_comp_g, u0_comp_bt, u0_comp_m, u0_comp_v, comp, 48 * 80);
    enc_fpn<<<dim3(660), blk, 0, stream>>>(420,
        comp, wt_enc0, u0_enc_g, u0_enc_bt, u0_enc_m, u0_enc_v, enc, 48, 80, 5,
        lat1p, wt_fpn1, fpn1_b, out1, 48, 80, 5);
    carafe_kernel<2, false><<<dim3(10, 6, 8), blk, 0, stream>>>(lat1, enc, lat0, lat0p, 48, 80);

    // 5) final fpn: level0 only (960 blocks)
    fpn_multi<<<dim3(960), blk, 0, stream>>>(lat0p, wt_fpn0, fpn0_b, out0);
}

// Round 7
// 287.206 us; speedup vs baseline: 1.2161x; 1.1230x over previous
//
#include <hip/hip_runtime.h>

#define BN_EPS 1e-5f

typedef __attribute__((ext_vector_type(8))) short bf16x8;
typedef __attribute__((ext_vector_type(4))) float f32x4;

__device__ __forceinline__ unsigned short f2bf(float f) {
    unsigned u = __float_as_uint(f);
    return (unsigned short)((u + 0x7fffu + ((u >> 16) & 1u)) >> 16);   // RNE
}
__device__ __forceinline__ unsigned packbf(float lo, float hi) {
    return ((unsigned)f2bf(hi) << 16) | (unsigned)f2bf(lo);
}

// ---------------------------------------------------------------------------
// Weight prep (ONE launch): conv3x3 -> wt[tap][co][ci] bf16; 1x1 -> bf16 cast
// grid (252, 10), block 256
// ---------------------------------------------------------------------------
__global__ __launch_bounds__(256)
void prep_weights(const float* __restrict__ w0, const float* __restrict__ w1,
                  const float* __restrict__ w2, const float* __restrict__ w3,
                  const float* __restrict__ w4, unsigned short* __restrict__ dst,
                  const float* __restrict__ v0, const float* __restrict__ v1,
                  const float* __restrict__ v2, const float* __restrict__ v3,
                  const float* __restrict__ v4, unsigned short* __restrict__ dst1)
{
    int z = blockIdx.y;
    int i = blockIdx.x * 256 + threadIdx.x;
    if (z < 5) {
        const float* src; unsigned short* d; int C_out, COP;
        if (z < 3) {
            COP = 64; C_out = 64;
            src = (z == 0) ? w0 : (z == 1 ? w1 : w2);
            d = dst + z * 36864;
            if (i >= 36864) return;
        } else {
            COP = 112; C_out = 100;
            src = (z == 3) ? w3 : w4;
            d = dst + 110592 + (z - 3) * 64512;
            if (i >= 64512) return;
        }
        int tap = i / (COP * 64);
        int rem = i - tap * (COP * 64);
        int co = rem >> 6, ci = rem & 63;
        float v = (co < C_out) ? src[((size_t)co * 64 + ci) * 9 + tap] : 0.f;
        d[i] = f2bf(v);
    } else {
        int zz = z - 5;
        const float* s; int n; int off;
        if (zz == 0)      { s = v0; n = 8192;  off = 0; }
        else if (zz == 1) { s = v1; n = 16384; off = 8192; }
        else if (zz == 2) { s = v2; n = 32768; off = 24576; }
        else if (zz == 3) { s = v3; n = 4096;  off = 57344; }
        else              { s = v4; n = 4096;  off = 61440; }
        if (i >= n) return;
        dst1[off + i] = f2bf(s[i]);
    }
}

// ---------------------------------------------------------------------------
// conv3x3 body (bf16 MFMA 16x16x32, C_in=64, fp32 acc).  LDS 20736 B.
// R16: split-K staging (32 ch at a time), persistent accumulators.
// R18: PACKED — bf16 channel-pair-packed mirror input [b][cp=32][H][W] u32.
// R20: ALL conv3x3 users are now PACKED (enc reads comp's mirror).
// CPB stays 1 (R1/R2 VGPR cliff).
// ---------------------------------------------------------------------------
template<int COP, int CSPLIT, int MODE>
__device__ __forceinline__
void conv3x3_body(int rem, int TX, unsigned short* xs,
                  const unsigned* __restrict__ xp,
                  const unsigned short* __restrict__ wt,
                  const float* __restrict__ p0, const float* __restrict__ p1,
                  const float* __restrict__ p2, const float* __restrict__ p3,
                  float* __restrict__ out, int H, int W, int C_out)
{
    constexpr int NP = 324;
    constexpr int CT = COP / 16;
    static_assert(CT == CSPLIT, "CPB must be 1 (R1/R2 VGPR cliff)");

    int cs = rem % CSPLIT;
    int b  = (rem / CSPLIT) & 3;
    int t  = rem / (CSPLIT * 4);
    int x0 = (t % TX) * 16, y0 = (t / TX) * 16;

    int tid  = threadIdx.x;
    int lane = tid & 63, wid = tid >> 6;
    int lrow = lane >> 4, lcol = lane & 15;
    int HWp = H * W;

    int co0 = cs * 16;
    bool colok = (x0 + lcol) < W;

    f32x4 accA[2], accB[2];
#pragma unroll
    for (int rr = 0; rr < 2; ++rr) {
        accA[rr] = (f32x4){0.f, 0.f, 0.f, 0.f};
        accB[rr] = (f32x4){0.f, 0.f, 0.f, 0.f};
    }

    unsigned int* wsl = (unsigned int*)xs;

#pragma unroll 1
    for (int kb = 0; kb < 2; ++kb) {
        if (kb) __syncthreads();          // protect xs before overwrite
        // ---- stage ch-pairs [kb*16, kb*16+16) of the 18x18 halo tile ----
        for (int p = tid; p < NP; p += 256) {
            int py = p / 18, px = p - py * 18;
            int gy = y0 + py - 1, gx = x0 + px - 1;
            bool ok = (gy >= 0) && (gy < H) && (gx >= 0) && (gx < W);
            const unsigned* gpp = xp + ((size_t)b * 32 + kb * 16) * HWp
                                     + (size_t)gy * W + gx;
#pragma unroll 8
            for (int cp = 0; cp < 16; ++cp) {
                unsigned pk = ok ? gpp[(size_t)cp * HWp] : 0u;
                wsl[((cp >> 2) * NP + p) * 4 + (cp & 3)] = pk;
            }
        }
        __syncthreads();

        // ---- weights for this K-half: 9 taps x 1 frag ----
        bf16x8 a[9];
        const unsigned short* wl = wt + ((size_t)co0 + lcol) * 64 + kb * 32 + lrow * 8;
#pragma unroll
        for (int t9 = 0; t9 < 9; ++t9)
            a[t9] = *(const bf16x8*)(wl + (size_t)t9 * COP * 64);

        // ---- 18 MFMAs into persistent accumulators ----
#pragma unroll
        for (int rr = 0; rr < 2; ++rr) {
            int r0 = wid + rr * 8;
#pragma unroll
            for (int t9 = 0; t9 < 9; ++t9) {
                int dy = t9 / 3, dx = t9 - dy * 3;
                int g0 = lrow * NP + (r0 + dy) * 18 + lcol + dx;
                bf16x8 b0 = *(const bf16x8*)(xs + (size_t)g0 * 8);
                accA[rr] = __builtin_amdgcn_mfma_f32_16x16x32_bf16(a[t9], b0, accA[rr], 0, 0, 0);
                bf16x8 b1 = *(const bf16x8*)(xs + ((size_t)g0 + 4 * 18) * 8);
                accB[rr] = __builtin_amdgcn_mfma_f32_16x16x32_bf16(a[t9], b1, accB[rr], 0, 0, 0);
            }
        }
    }

    // ---- epilogue: BN/bias + store ----
    float sc[4], sh[4];
#pragma unroll
    for (int rg = 0; rg < 4; ++rg) {
        int co = co0 + lrow * 4 + rg;
        int cc = (co < C_out) ? co : 0;
        if (MODE == 0) { sc[rg] = 1.f; sh[rg] = p0[cc]; }
        else {
            float inv = p0[cc] * rsqrtf(p3[cc] + BN_EPS);
            sc[rg] = inv; sh[rg] = p1[cc] - p2[cc] * inv;
        }
    }
#pragma unroll
    for (int rr = 0; rr < 2; ++rr) {
        int r0 = wid + rr * 8;
        int yA = y0 + r0, yB = y0 + r0 + 4;
#pragma unroll
        for (int rg = 0; rg < 4; ++rg) {
            int co = co0 + lrow * 4 + rg;
            if (colok && co < C_out) {
                float* oc = out + (((size_t)b * C_out + co) * H) * W + x0 + lcol;
                if (yA < H) oc[(size_t)yA * W] = accA[rr][rg] * sc[rg] + sh[rg];
                if (yB < H) oc[(size_t)yB * W] = accB[rr][rg] * sc[rg] + sh[rg];
            }
        }
    }
}

// R19/R20: enc conv3x3 (PACKED, reads comp mirror) + independent fpn level
// merged into ONE dispatch.  Blocks [0,encBlocks) = enc <112,7,1>; rest =
// fpn <64,4,0>.  Revert trigger: VGPR > ~64.
__global__ __launch_bounds__(256, 6)
void enc_fpn(int encBlocks,
             const unsigned* __restrict__ cxp, const unsigned short* __restrict__ wt_e,
             const float* __restrict__ g, const float* __restrict__ bt,
             const float* __restrict__ m, const float* __restrict__ v,
             float* __restrict__ enc_out, int He, int We, int TXe,
             const unsigned* __restrict__ xp, const unsigned short* __restrict__ wt_f,
             const float* __restrict__ bias, float* __restrict__ fout,
             int Hf, int Wf, int TXf)
{
    __shared__ unsigned short xs[4 * 324 * 8];
    int f = blockIdx.x;
    if (f < encBlocks)
        conv3x3_body<112, 7, 1>(f, TXe, xs, cxp, wt_e,
                                g, bt, m, v, enc_out, He, We, 100);
    else
        conv3x3_body<64, 4, 0>(f - encBlocks, TXf, xs, xp, wt_f,
                               bias, nullptr, nullptr, nullptr, fout, Hf, Wf, 64);
}

// final fpn: level0 only.  grid (960)
__global__ __launch_bounds__(256, 6)
void fpn_multi(const unsigned* __restrict__ l0p, const unsigned short* __restrict__ wt0,
               const float* __restrict__ b0, float* __restrict__ o0)
{
    __shared__ unsigned short xs[4 * 324 * 8];
    conv3x3_body<64, 4, 0>(blockIdx.x, 10, xs, l0p, wt0,
                           b0, nullptr, nullptr, nullptr, o0, 96, 160, 64);
}

// ---------------------------------------------------------------------------
// conv1x1 body (bf16 MFMA GEMM).  xs = 4*NPX*8 shorts of LDS.
// R20: float4-vectorized staging (4x fewer load insts, 4x bytes in flight);
// MIRROR epilogue writes bf16 pair-packed output only (comp layers — enc is
// the sole consumer and reads the mirror; f2bf moved here, bit-identical).
// ---------------------------------------------------------------------------
template<int C_IN, int KSPLIT, int NPX, int MODE, bool MIRROR>
__device__ __forceinline__
void conv1x1_body(int f, unsigned short* xs,
                  const float* __restrict__ x, const unsigned short* __restrict__ wb,
                  const float* __restrict__ p0, const float* __restrict__ p1,
                  const float* __restrict__ p2, const float* __restrict__ p3,
                  float* __restrict__ out, unsigned* __restrict__ outp, int HW)
{
    constexpr int NT = NPX / 16;
    constexpr int KLEN = C_IN / KSPLIT;
    constexpr int QUADS = NPX / 4;          // pow2
    int nb = HW / NPX;
    int px0 = (f % nb) * NPX;
    int ks  = (f / nb) % KSPLIT;
    int b   = f / (nb * KSPLIT);

    int tid = threadIdx.x;
    int lane = tid & 63, wid = tid >> 6;
    int lrow = lane >> 4, lcol = lane & 15;
    const float* xb = x + (size_t)b * C_IN * HW + px0;

    f32x4 acc[NT];
#pragma unroll
    for (int nt = 0; nt < NT; ++nt) acc[nt] = (f32x4){0.f, 0.f, 0.f, 0.f};

    for (int cc = 0; cc < KLEN; cc += 32) {
        if (cc) __syncthreads();
        int cb = ks * KLEN + cc;
        for (int j = tid; j < 16 * QUADS; j += 256) {
            int q  = j & (QUADS - 1);
            int cp = j / QUADS;
            int px = q * 4;
            const float* s0 = xb + (size_t)(cb + 2 * cp) * HW + px;
            float4 v0 = *(const float4*)s0;
            float4 v1 = *(const float4*)(s0 + HW);
            unsigned* wv = (unsigned*)xs + ((size_t)(cp >> 2) * NPX + px) * 4 + (cp & 3);
            wv[0]  = packbf(v0.x, v1.x);
            wv[4]  = packbf(v0.y, v1.y);
            wv[8]  = packbf(v0.z, v1.z);
            wv[12] = packbf(v0.w, v1.w);
        }
        __syncthreads();

        bf16x8 a = *(const bf16x8*)(wb + (size_t)(wid * 16 + lcol) * C_IN + cb + lrow * 8);
#pragma unroll
        for (int nt = 0; nt < NT; ++nt) {
            bf16x8 bf = *(const bf16x8*)(xs + ((size_t)lrow * NPX + nt * 16 + lcol) * 8);
            acc[nt] = __builtin_amdgcn_mfma_f32_16x16x32_bf16(a, bf, acc[nt], 0, 0, 0);
        }
    }

    if (KSPLIT == 1) {
        if (MIRROR) {
            // packed bf16 mirror only ([b][cp=32][HW] u32); MODE==1 (BN+ReLU)
#pragma unroll
            for (int rg = 0; rg < 4; rg += 2) {
                int co = wid * 16 + lrow * 4 + rg;
                float inv0 = p0[co] * rsqrtf(p3[co] + BN_EPS);
                float sh0  = p1[co] - p2[co] * inv0;
                float inv1 = p0[co + 1] * rsqrtf(p3[co + 1] + BN_EPS);
                float sh1  = p1[co + 1] - p2[co + 1] * inv1;
                unsigned* pp = outp + ((size_t)(b * 32 + (co >> 1))) * HW + px0;
#pragma unroll
                for (int nt = 0; nt < NT; ++nt) {
                    float r0 = fmaxf(acc[nt][rg] * inv0 + sh0, 0.f);
                    float r1 = fmaxf(acc[nt][rg + 1] * inv1 + sh1, 0.f);
                    pp[nt * 16 + lcol] = packbf(r0, r1);
                }
            }
        } else {
#pragma unroll
            for (int rg = 0; rg < 4; ++rg) {
                int co = wid * 16 + lrow * 4 + rg;
                float scale, shift;
                if (MODE == 0) { scale = 1.f; shift = p0[co]; }
                else {
                    float inv = p0[co] * rsqrtf(p3[co] + BN_EPS);
                    scale = inv; shift = p1[co] - p2[co] * inv;
                }
                float* op = out + ((size_t)(b * 64 + co)) * HW + px0;
#pragma unroll
                for (int nt = 0; nt < NT; ++nt) {
                    float r = acc[nt][rg] * scale + shift;
                    if (MODE == 1) r = fmaxf(r, 0.f);
                    op[nt * 16 + lcol] = r;
                }
            }
        }
    } else {
#pragma unroll
        for (int rg = 0; rg < 4; ++rg) {
            int co = wid * 16 + lrow * 4 + rg;
            float* op = out + (((size_t)(ks * 4 + b)) * 64 + co) * HW + px0;
#pragma unroll
            for (int nt = 0; nt < NT; ++nt)
                op[nt * 16 + lcol] = acc[nt][rg];
        }
    }
}

// standalone conv1x1 (comp layers), grid (HW/NPX, 1, B)
template<int C_IN, int KSPLIT, int NPX, int MODE, bool MIRROR>
__global__ __launch_bounds__(256, 4)
void conv1x1_mfma(const float* __restrict__ x, const unsigned short* __restrict__ wb,
                  const float* __restrict__ p0, const float* __restrict__ p1,
                  const float* __restrict__ p2, const float* __restrict__ p3,
                  float* __restrict__ out, unsigned* __restrict__ outp, int HW)
{
    __shared__ __align__(16) unsigned short xs[4 * NPX * 8];
    int nb = HW / NPX;
    int f = blockIdx.x + nb * (blockIdx.y + KSPLIT * blockIdx.z);
    conv1x1_body<C_IN, KSPLIT, NPX, MODE, MIRROR>(f, xs, x, wb, p0, p1, p2, p3, out, outp, HW);
}

// fused lateral convs: lat0 [0,480), lat1->part [480,720), lat2->part [720,960)
__global__ __launch_bounds__(256, 4)
void lat_multi(const float* __restrict__ x0, const unsigned short* __restrict__ w0,
               const float* __restrict__ b0, float* __restrict__ lat0,
               const float* __restrict__ x1, const unsigned short* __restrict__ w1,
               float* __restrict__ part1,
               const float* __restrict__ x2, const unsigned short* __restrict__ w2,
               float* __restrict__ part2)
{
    __shared__ __align__(16) unsigned short xs[4 * 128 * 8];
    int f = blockIdx.x;
    if (f < 480)
        conv1x1_body<128, 1, 128, 0, false>(f, xs, x0, w0, b0, nullptr, nullptr, nullptr, lat0, nullptr, 15360);
    else if (f < 720)
        conv1x1_body<256, 2, 128, 0, false>(f - 480, xs, x1, w1, nullptr, nullptr, nullptr, nullptr, part1, nullptr, 3840);
    else
        conv1x1_body<512, 4, 64, 0, false>(f - 720, xs, x2, w2, nullptr, nullptr, nullptr, nullptr, part2, nullptr, 960);
}

// ---------------------------------------------------------------------------
// K-split reduce + bias.  lat1: plain fp32 (f in [0,960)).
// lat2: fp32 + bf16 pair-packed mirror (f in [960,1080)).
// ---------------------------------------------------------------------------
template<int KSPLIT>
__device__ __forceinline__
void reduce_body(int f, const float* __restrict__ part, const float* __restrict__ bias,
                 float* __restrict__ out, int HW, int N4)
{
    int i = f * 256 + threadIdx.x;
    if (i >= N4) return;
    size_t base = (size_t)i * 4;
    int co = (int)((base / (size_t)HW) & 63);
    size_t stride = (size_t)HW << 8;
    float4 s = *(const float4*)(part + base);
#pragma unroll
    for (int ks = 1; ks < KSPLIT; ++ks) {
        float4 t = *(const float4*)(part + (size_t)ks * stride + base);
        s.x += t.x; s.y += t.y; s.z += t.z; s.w += t.w;
    }
    float bv = bias[co];
    s.x += bv; s.y += bv; s.z += bv; s.w += bv;
    *(float4*)(out + base) = s;
}

__device__ __forceinline__
void reduce_pack4(int f, const float* __restrict__ part, const float* __restrict__ bias,
                  float* __restrict__ out, unsigned* __restrict__ outp, int HW, int N)
{
    int i = f * 256 + threadIdx.x;
    if (i >= N) return;                    // N = 4b * 32cp * (HW/4)
    int q = HW >> 2;
    int pxq  = i % q;
    int rest = i / q;                      // b*32 + cp
    int cp = rest & 31, b = rest >> 5;
    size_t off = (size_t)pxq * 4;
    size_t c0 = ((size_t)(b * 64 + 2 * cp)) * HW + off;
    size_t stride = (size_t)HW << 8;
    float4 s0 = *(const float4*)(part + c0);
    float4 s1 = *(const float4*)(part + c0 + HW);
#pragma unroll
    for (int ks = 1; ks < 4; ++ks) {
        float4 t0 = *(const float4*)(part + (size_t)ks * stride + c0);
        float4 t1 = *(const float4*)(part + (size_t)ks * stride + c0 + HW);
        s0.x += t0.x; s0.y += t0.y; s0.z += t0.z; s0.w += t0.w;
        s1.x += t1.x; s1.y += t1.y; s1.z += t1.z; s1.w += t1.w;
    }
    float bv0 = bias[2 * cp], bv1 = bias[2 * cp + 1];
    s0.x += bv0; s0.y += bv0; s0.z += bv0; s0.w += bv0;
    s1.x += bv1; s1.y += bv1; s1.z += bv1; s1.w += bv1;
    *(float4*)(out + c0) = s0;
    *(float4*)(out + c0 + HW) = s1;
    uint4 pk;
    pk.x = packbf(s0.x, s1.x);
    pk.y = packbf(s0.y, s1.y);
    pk.z = packbf(s0.z, s1.z);
    pk.w = packbf(s0.w, s1.w);
    *(uint4*)(outp + ((size_t)(b * 32 + cp)) * HW + off) = pk;
}

__global__ __launch_bounds__(256)
void reduce_multi(const float* __restrict__ part1, const float* __restrict__ b1,
                  float* __restrict__ lat1,
                  const float* __restrict__ part2, const float* __restrict__ b2,
                  float* __restrict__ lat2, unsigned* __restrict__ lat2p)
{
    int f = blockIdx.x;
    if (f < 960) reduce_body<2>(f, part1, b1, lat1, 3840, 245760);
    else         reduce_pack4(f - 960, part2, b2, lat2, lat2p, 960, 30720);
}

// ---------------------------------------------------------------------------
// CARAFE v5: channel-group split + bf16 mirror write.
// WF32: also write fp32 dst.  u0 (dst=lat0): WF32=false — fpn0 reads only the
// mirror.  bounds 4 (R4: 6 regressed, ~80 live VGPR).
// grid: (2w/16, 2h/16, B * CGS), block 256
// ---------------------------------------------------------------------------
template<int CGS, bool WF32>
__global__ __launch_bounds__(256, 4)
void carafe_kernel(const float* __restrict__ src, const float* __restrict__ logits,
                   float* __restrict__ dst, unsigned* __restrict__ dstp, int h, int w)
{
    constexpr int SW = 12, NPX = 144;
    constexpr int CH = 64 / CGS;
    constexpr int CS = CH + 4;
    __shared__ float ls[NPX * CS];

    int tid = threadIdx.x;
    int x0 = blockIdx.x * 16, y0 = blockIdx.y * 16;
    int b  = blockIdx.z / CGS;
    int cs = blockIdx.z % CGS;
    int H = 2 * h, W = 2 * w;
    int xs0 = (x0 >> 1) - 2, ys0 = (y0 >> 1) - 2;
    size_t hw = (size_t)h * w;
    const float* sb = src + ((size_t)(b * 64 + cs * CH)) * hw;

    for (int i = tid; i < NPX * CH; i += 256) {
        int c = i / NPX, p = i - c * NPX;
        int yy = p / SW, xx = p - yy * SW;
        int sy = ys0 + yy, sx = xs0 + xx;
        float v = 0.f;
        if (sy >= 0 && sy < h && sx >= 0 && sx < w)
            v = sb[(size_t)c * hw + (size_t)sy * w + sx];
        ls[p * CS + c] = v;
    }
    __syncthreads();

    int lx = tid & 15, ty = tid >> 4;
    int x = x0 + lx, y = y0 + ty;
    int xw = x >> 1, yh = y >> 1;
    int par = (y & 1) * 2 + (x & 1);

    const float* lp = logits + ((size_t)(b * 100 + par) * h + yh) * w + xw;
    float l[25];
    float mx = -1e30f;
#pragma unroll
    for (int k = 0; k < 25; ++k) {
        l[k] = lp[(size_t)(4 * k) * hw];
        mx = fmaxf(mx, l[k]);
    }
    float s = 0.f;
#pragma unroll
    for (int k = 0; k < 25; ++k) {
        l[k] = __expf(l[k] - mx);
        s += l[k];
    }
    float invs = 1.f / s;
#pragma unroll
    for (int k = 0; k < 25; ++k) l[k] *= invs;

    int pb = (yh - ys0 - 2) * SW + (xw - xs0 - 2);

#pragma unroll 1
    for (int cg = 0; cg < CH / 16; ++cg) {
        float acc[16];
#pragma unroll
        for (int c = 0; c < 16; ++c) acc[c] = 0.f;
#pragma unroll
        for (int k = 0; k < 25; ++k) {
            int ti = k / 5, tj = k - ti * 5;
            const float* q = &ls[(pb + ti * SW + tj) * CS + cg * 16];
            float wk = l[k];
#pragma unroll
            for (int c = 0; c < 16; ++c)
                acc[c] = fmaf(wk, q[c], acc[c]);
        }
        int cbase = cs * CH + cg * 16;
        float* dp = dst + (((size_t)(b * 64 + cbase)) * H + y) * W + x;
        unsigned* pp = dstp + (((size_t)(b * 32 + (cbase >> 1))) * H + y) * W + x;
#pragma unroll
        for (int c = 0; c < 16; c += 2) {
            float n0 = dp[(size_t)c * H * W] + acc[c];
            float n1 = dp[(size_t)(c + 1) * H * W] + acc[c + 1];
            if (WF32) {
                dp[(size_t)c * H * W] = n0;
                dp[(size_t)(c + 1) * H * W] = n1;
            }
            pp[(size_t)(c >> 1) * H * W] = packbf(n0, n1);
        }
    }
}

// ---------------------------------------------------------------------------
extern "C" void kernel_launch(void* const* d_in, const int* in_sizes, int n_in,
                              void* d_out, int out_size, void* d_ws, size_t ws_size,
                              hipStream_t stream)
{
    const float* x0      = (const float*)d_in[0];
    const float* lat0_w  = (const float*)d_in[1];
    const float* lat0_b  = (const float*)d_in[2];
    const float* fpn0_w  = (const float*)d_in[3];
    const float* fpn0_b  = (const float*)d_in[4];
    const float* x1      = (const float*)d_in[5];
    const float* lat1_w  = (const float*)d_in[6];
    const float* lat1_b  = (const float*)d_in[7];
    const float* fpn1_w  = (const float*)d_in[8];
    const float* fpn1_b  = (const float*)d_in[9];
    const float* x2      = (const float*)d_in[10];
    const float* lat2_w  = (const float*)d_in[11];
    const float* lat2_b  = (const float*)d_in[12];
    const float* fpn2_w  = (const float*)d_in[13];
    const float* fpn2_b  = (const float*)d_in[14];
    const float* u0_comp_w = (const float*)d_in[15];
    const float* u0_enc_w  = (const float*)d_in[16];
    const float* u0_comp_g  = (const float*)d_in[17];
    const float* u0_comp_bt = (const float*)d_in[18];
    const float* u0_comp_m  = (const float*)d_in[19];
    const float* u0_comp_v  = (const float*)d_in[20];
    const float* u0_enc_g   = (const float*)d_in[21];
    const float* u0_enc_bt  = (const float*)d_in[22];
    const float* u0_enc_m   = (const float*)d_in[23];
    const float* u0_enc_v   = (const float*)d_in[24];
    const float* u1_comp_w = (const float*)d_in[25];
    const float* u1_enc_w  = (const float*)d_in[26];
    const float* u1_comp_g  = (const float*)d_in[27];
    const float* u1_comp_bt = (const float*)d_in[28];
    const float* u1_comp_m  = (const float*)d_in[29];
    const float* u1_comp_v  = (const float*)d_in[30];
    const float* u1_enc_g   = (const float*)d_in[31];
    const float* u1_enc_bt  = (const float*)d_in[32];
    const float* u1_enc_m   = (const float*)d_in[33];
    const float* u1_enc_v   = (const float*)d_in[34];

    float* out = (float*)d_out;
    const size_t OUT0 = 4ull * 64 * 96 * 160;   // 3,932,160
    const size_t OUT1 = 4ull * 64 * 48 * 80;    //   983,040
    const size_t OUT2 = 4ull * 64 * 24 * 40;    //   245,760
    float* out0 = out;
    float* out1 = out + OUT0;
    float* out2 = out + OUT0 + OUT1;

    float* lat0 = (float*)d_ws;
    float* lat1 = lat0 + OUT0;
    float* lat2 = lat1 + OUT1;
    unsigned short* wtb = (unsigned short*)(lat2 + OUT2);   // 239,616 bf16
    unsigned short* wt_fpn0 = wtb;
    unsigned short* wt_fpn1 = wtb + 36864;
    unsigned short* wt_fpn2 = wtb + 73728;
    unsigned short* wt_enc0 = wtb + 110592;
    unsigned short* wt_enc1 = wtb + 175104;
    unsigned short* wb = wtb + 239616;                      // 65,536 bf16 (1x1)
    unsigned short* wb_lat0  = wb;
    unsigned short* wb_lat1  = wb + 8192;
    unsigned short* wb_lat2  = wb + 24576;
    unsigned short* wb_comp0 = wb + 57344;
    unsigned short* wb_comp1 = wb + 61440;
    // bf16 channel-pair-packed mirrors ([b][cp=32][H][W] u32):
    unsigned* lat0p = (unsigned*)(wb + 65536);              // 1,966,080 u32
    unsigned* lat1p = lat0p + 1966080;                      //   491,520 u32
    unsigned* lat2p = lat1p + 491520;                       //   122,880 u32
    unsigned* compp = lat2p + 122880;                       //   491,520 u32 (max)
    // out0 region doubles as scratch (fpn0 overwrites it LAST):
    float* part1 = out0;                 // lat1 partials: 2*983,040
    float* part2 = out0 + 2 * OUT1;      // lat2 partials: 4*245,760
    float* enc   = out0 + OUT1;          // enc logits (after reduces consume parts)

    dim3 blk(256);

    // 0) weight prep
    prep_weights<<<dim3(252, 10), blk, 0, stream>>>(
        fpn0_w, fpn1_w, fpn2_w, u0_enc_w, u1_enc_w, wtb,
        lat0_w, lat1_w, lat2_w, u0_comp_w, u1_comp_w, wb);

    // 1) all three lateral 1x1 convs — ONE dispatch (960 blocks)
    lat_multi<<<dim3(960), blk, 0, stream>>>(
        x0, wb_lat0, lat0_b, lat0, x1, wb_lat1, part1, x2, wb_lat2, part2);

    // 2) both K-split reduces (lat2 also emits bf16 mirror) — ONE dispatch
    reduce_multi<<<dim3(1080), blk, 0, stream>>>(
        part1, lat1_b, lat1, part2, lat2_b, lat2, lat2p);

    // 3) CARAFE u1: lat1 += carafe(lat2); fpn2 rides with enc1 (backfill)
    conv1x1_mfma<64, 1, 32, 1, true><<<dim3(30, 1, 4), blk, 0, stream>>>(
        lat2, wb_comp1, u1_comp_g, u1_comp_bt, u1_comp_m, u1_comp_v, nullptr, compp, 24 * 40);
    enc_fpn<<<dim3(264), blk, 0, stream>>>(168,
        compp, wt_enc1, u1_enc_g, u1_enc_bt, u1_enc_m, u1_enc_v, enc, 24, 40, 3,
        lat2p, wt_fpn2, fpn2_b, out2, 24, 40, 3);
    carafe_kernel<2, true><<<dim3(5, 3, 8), blk, 0, stream>>>(lat2, enc, lat1, lat1p, 24, 40);

    // 4) CARAFE u0: lat0 += carafe(lat1); fpn1 rides with enc0 (backfill)
    conv1x1_mfma<64, 1, 32, 1, true><<<dim3(120, 1, 4), blk, 0, stream>>>(
        lat1, wb_comp0, u0_comp_g, u0_comp_bt, u0_comp_m, u0_comp_v, nullptr, compp, 48 * 80);
    enc_fpn<<<dim3(660), blk, 0, stream>>>(420,
        compp, wt_enc0, u0_enc_g, u0_enc_bt, u0_enc_m, u0_enc_v, enc, 48, 80, 5,
        lat1p, wt_fpn1, fpn1_b, out1, 48, 80, 5);
    carafe_kernel<2, false><<<dim3(10, 6, 8), blk, 0, stream>>>(lat1, enc, lat0, lat0p, 48, 80);

    // 5) final fpn: level0 only (960 blocks)
    fpn_multi<<<dim3(960), blk, 0, stream>>>(lat0p, wt_fpn0, fpn0_b, out0);
}

// Round 8
// 276.196 us; speedup vs baseline: 1.2646x; 1.0399x over previous
//
#include <hip/hip_runtime.h>

#define BN_EPS 1e-5f

typedef __attribute__((ext_vector_type(8))) short bf16x8;
typedef __attribute__((ext_vector_type(4))) float f32x4;

__device__ __forceinline__ unsigned short f2bf(float f) {
    unsigned u = __float_as_uint(f);
    return (unsigned short)((u + 0x7fffu + ((u >> 16) & 1u)) >> 16);   // RNE
}
__device__ __forceinline__ unsigned packbf(float lo, float hi) {
    return ((unsigned)f2bf(hi) << 16) | (unsigned)f2bf(lo);
}

// ---------------------------------------------------------------------------
// Weight prep (ONE launch): conv3x3 -> wt[tap][co][ci] bf16; 1x1 -> bf16 cast
// grid (252, 10), block 256
// ---------------------------------------------------------------------------
__global__ __launch_bounds__(256)
void prep_weights(const float* __restrict__ w0, const float* __restrict__ w1,
                  const float* __restrict__ w2, const float* __restrict__ w3,
                  const float* __restrict__ w4, unsigned short* __restrict__ dst,
                  const float* __restrict__ v0, const float* __restrict__ v1,
                  const float* __restrict__ v2, const float* __restrict__ v3,
                  const float* __restrict__ v4, unsigned short* __restrict__ dst1)
{
    int z = blockIdx.y;
    int i = blockIdx.x * 256 + threadIdx.x;
    if (z < 5) {
        const float* src; unsigned short* d; int C_out, COP;
        if (z < 3) {
            COP = 64; C_out = 64;
            src = (z == 0) ? w0 : (z == 1 ? w1 : w2);
            d = dst + z * 36864;
            if (i >= 36864) return;
        } else {
            COP = 112; C_out = 100;
            src = (z == 3) ? w3 : w4;
            d = dst + 110592 + (z - 3) * 64512;
            if (i >= 64512) return;
        }
        int tap = i / (COP * 64);
        int rem = i - tap * (COP * 64);
        int co = rem >> 6, ci = rem & 63;
        float v = (co < C_out) ? src[((size_t)co * 64 + ci) * 9 + tap] : 0.f;
        d[i] = f2bf(v);
    } else {
        int zz = z - 5;
        const float* s; int n; int off;
        if (zz == 0)      { s = v0; n = 8192;  off = 0; }
        else if (zz == 1) { s = v1; n = 16384; off = 8192; }
        else if (zz == 2) { s = v2; n = 32768; off = 24576; }
        else if (zz == 3) { s = v3; n = 4096;  off = 57344; }
        else              { s = v4; n = 4096;  off = 61440; }
        if (i >= n) return;
        dst1[off + i] = f2bf(s[i]);
    }
}

// ---------------------------------------------------------------------------
// conv3x3 body (bf16 MFMA 16x16x32, C_in=64, fp32 acc).  LDS 20736 B.
// R16 split-K staging; R18/R20 PACKED mirror input [b][cp=32][H][W] u32.
// CPB stays 1 (R1/R2 VGPR cliff).
// ---------------------------------------------------------------------------
template<int COP, int CSPLIT, int MODE>
__device__ __forceinline__
void conv3x3_body(int rem, int TX, unsigned short* xs,
                  const unsigned* __restrict__ xp,
                  const unsigned short* __restrict__ wt,
                  const float* __restrict__ p0, const float* __restrict__ p1,
                  const float* __restrict__ p2, const float* __restrict__ p3,
                  float* __restrict__ out, int H, int W, int C_out)
{
    constexpr int NP = 324;
    constexpr int CT = COP / 16;
    static_assert(CT == CSPLIT, "CPB must be 1 (R1/R2 VGPR cliff)");

    int cs = rem % CSPLIT;
    int b  = (rem / CSPLIT) & 3;
    int t  = rem / (CSPLIT * 4);
    int x0 = (t % TX) * 16, y0 = (t / TX) * 16;

    int tid  = threadIdx.x;
    int lane = tid & 63, wid = tid >> 6;
    int lrow = lane >> 4, lcol = lane & 15;
    int HWp = H * W;

    int co0 = cs * 16;
    bool colok = (x0 + lcol) < W;

    f32x4 accA[2], accB[2];
#pragma unroll
    for (int rr = 0; rr < 2; ++rr) {
        accA[rr] = (f32x4){0.f, 0.f, 0.f, 0.f};
        accB[rr] = (f32x4){0.f, 0.f, 0.f, 0.f};
    }

    unsigned int* wsl = (unsigned int*)xs;

#pragma unroll 1
    for (int kb = 0; kb < 2; ++kb) {
        if (kb) __syncthreads();          // protect xs before overwrite
        // ---- stage ch-pairs [kb*16, kb*16+16) of the 18x18 halo tile ----
        for (int p = tid; p < NP; p += 256) {
            int py = p / 18, px = p - py * 18;
            int gy = y0 + py - 1, gx = x0 + px - 1;
            bool ok = (gy >= 0) && (gy < H) && (gx >= 0) && (gx < W);
            const unsigned* gpp = xp + ((size_t)b * 32 + kb * 16) * HWp
                                     + (size_t)gy * W + gx;
#pragma unroll 8
            for (int cp = 0; cp < 16; ++cp) {
                unsigned pk = ok ? gpp[(size_t)cp * HWp] : 0u;
                wsl[((cp >> 2) * NP + p) * 4 + (cp & 3)] = pk;
            }
        }
        __syncthreads();

        // ---- weights for this K-half: 9 taps x 1 frag ----
        bf16x8 a[9];
        const unsigned short* wl = wt + ((size_t)co0 + lcol) * 64 + kb * 32 + lrow * 8;
#pragma unroll
        for (int t9 = 0; t9 < 9; ++t9)
            a[t9] = *(const bf16x8*)(wl + (size_t)t9 * COP * 64);

        // ---- 18 MFMAs into persistent accumulators ----
#pragma unroll
        for (int rr = 0; rr < 2; ++rr) {
            int r0 = wid + rr * 8;
#pragma unroll
            for (int t9 = 0; t9 < 9; ++t9) {
                int dy = t9 / 3, dx = t9 - dy * 3;
                int g0 = lrow * NP + (r0 + dy) * 18 + lcol + dx;
                bf16x8 b0 = *(const bf16x8*)(xs + (size_t)g0 * 8);
                accA[rr] = __builtin_amdgcn_mfma_f32_16x16x32_bf16(a[t9], b0, accA[rr], 0, 0, 0);
                bf16x8 b1 = *(const bf16x8*)(xs + ((size_t)g0 + 4 * 18) * 8);
                accB[rr] = __builtin_amdgcn_mfma_f32_16x16x32_bf16(a[t9], b1, accB[rr], 0, 0, 0);
            }
        }
    }

    // ---- epilogue: BN/bias + store ----
    float sc[4], sh[4];
#pragma unroll
    for (int rg = 0; rg < 4; ++rg) {
        int co = co0 + lrow * 4 + rg;
        int cc = (co < C_out) ? co : 0;
        if (MODE == 0) { sc[rg] = 1.f; sh[rg] = p0[cc]; }
        else {
            float inv = p0[cc] * rsqrtf(p3[cc] + BN_EPS);
            sc[rg] = inv; sh[rg] = p1[cc] - p2[cc] * inv;
        }
    }
#pragma unroll
    for (int rr = 0; rr < 2; ++rr) {
        int r0 = wid + rr * 8;
        int yA = y0 + r0, yB = y0 + r0 + 4;
#pragma unroll
        for (int rg = 0; rg < 4; ++rg) {
            int co = co0 + lrow * 4 + rg;
            if (colok && co < C_out) {
                float* oc = out + (((size_t)b * C_out + co) * H) * W + x0 + lcol;
                if (yA < H) oc[(size_t)yA * W] = accA[rr][rg] * sc[rg] + sh[rg];
                if (yB < H) oc[(size_t)yB * W] = accB[rr][rg] * sc[rg] + sh[rg];
            }
        }
    }
}

// enc conv3x3 (PACKED, reads comp mirror) + independent fpn level in ONE
// dispatch.  Blocks [0,encBlocks) = enc <112,7,1>; rest = fpn <64,4,0>.
__global__ __launch_bounds__(256, 6)
void enc_fpn(int encBlocks,
             const unsigned* __restrict__ cxp, const unsigned short* __restrict__ wt_e,
             const float* __restrict__ g, const float* __restrict__ bt,
             const float* __restrict__ m, const float* __restrict__ v,
             float* __restrict__ enc_out, int He, int We, int TXe,
             const unsigned* __restrict__ xp, const unsigned short* __restrict__ wt_f,
             const float* __restrict__ bias, float* __restrict__ fout,
             int Hf, int Wf, int TXf)
{
    __shared__ unsigned short xs[4 * 324 * 8];
    int f = blockIdx.x;
    if (f < encBlocks)
        conv3x3_body<112, 7, 1>(f, TXe, xs, cxp, wt_e,
                                g, bt, m, v, enc_out, He, We, 100);
    else
        conv3x3_body<64, 4, 0>(f - encBlocks, TXf, xs, xp, wt_f,
                               bias, nullptr, nullptr, nullptr, fout, Hf, Wf, 64);
}

// final fpn: level0 only.  grid (960)
__global__ __launch_bounds__(256, 6)
void fpn_multi(const unsigned* __restrict__ l0p, const unsigned short* __restrict__ wt0,
               const float* __restrict__ b0, float* __restrict__ o0)
{
    __shared__ unsigned short xs[4 * 324 * 8];
    conv3x3_body<64, 4, 0>(blockIdx.x, 10, xs, l0p, wt0,
                           b0, nullptr, nullptr, nullptr, o0, 96, 160, 64);
}

// ---------------------------------------------------------------------------
// conv1x1 body (bf16 MFMA GEMM).  R21: KSPLIT removed (full K in-kernel —
// reduce_multi deleted).  INPK: input is bf16 pair-packed mirror (uint4
// staging, no f2bf).  OUTMIR: write bf16 pair-packed mirror only.
// ---------------------------------------------------------------------------
template<int C_IN, int NPX, int MODE, bool INPK, bool OUTMIR>
__device__ __forceinline__
void conv1x1_body(int f, unsigned short* xs,
                  const float* __restrict__ x, const unsigned* __restrict__ xp,
                  const unsigned short* __restrict__ wb,
                  const float* __restrict__ p0, const float* __restrict__ p1,
                  const float* __restrict__ p2, const float* __restrict__ p3,
                  float* __restrict__ out, unsigned* __restrict__ outp, int HW)
{
    constexpr int NT = NPX / 16;
    constexpr int QUADS = NPX / 4;          // pow2
    int nb = HW / NPX;
    int px0 = (f % nb) * NPX;
    int b   = f / nb;

    int tid = threadIdx.x;
    int lane = tid & 63, wid = tid >> 6;
    int lrow = lane >> 4, lcol = lane & 15;
    const float*    xb  = INPK ? nullptr : x + (size_t)b * C_IN * HW + px0;
    const unsigned* xpb = INPK ? xp + (size_t)b * (C_IN / 2) * HW + px0 : nullptr;

    f32x4 acc[NT];
#pragma unroll
    for (int nt = 0; nt < NT; ++nt) acc[nt] = (f32x4){0.f, 0.f, 0.f, 0.f};

    for (int cc = 0; cc < C_IN; cc += 32) {
        if (cc) __syncthreads();
        for (int j = tid; j < 16 * QUADS; j += 256) {
            int q  = j & (QUADS - 1);
            int cp = j / QUADS;
            int px = q * 4;
            unsigned* wv = (unsigned*)xs + ((size_t)(cp >> 2) * NPX + px) * 4 + (cp & 3);
            if (INPK) {
                uint4 v = *(const uint4*)(xpb + (size_t)(cc / 2 + cp) * HW + px);
                wv[0] = v.x; wv[4] = v.y; wv[8] = v.z; wv[12] = v.w;
            } else {
                const float* s0 = xb + (size_t)(cc + 2 * cp) * HW + px;
                float4 v0 = *(const float4*)s0;
                float4 v1 = *(const float4*)(s0 + HW);
                wv[0]  = packbf(v0.x, v1.x);
                wv[4]  = packbf(v0.y, v1.y);
                wv[8]  = packbf(v0.z, v1.z);
                wv[12] = packbf(v0.w, v1.w);
            }
        }
        __syncthreads();

        bf16x8 a = *(const bf16x8*)(wb + (size_t)(wid * 16 + lcol) * C_IN + cc + lrow * 8);
#pragma unroll
        for (int nt = 0; nt < NT; ++nt) {
            bf16x8 bf = *(const bf16x8*)(xs + ((size_t)lrow * NPX + nt * 16 + lcol) * 8);
            acc[nt] = __builtin_amdgcn_mfma_f32_16x16x32_bf16(a, bf, acc[nt], 0, 0, 0);
        }
    }

    if (OUTMIR) {
#pragma unroll
        for (int rg = 0; rg < 4; rg += 2) {
            int co = wid * 16 + lrow * 4 + rg;
            float s0, h0, s1, h1;
            if (MODE == 0) { s0 = 1.f; h0 = p0[co]; s1 = 1.f; h1 = p0[co + 1]; }
            else {
                s0 = p0[co] * rsqrtf(p3[co] + BN_EPS);
                h0 = p1[co] - p2[co] * s0;
                s1 = p0[co + 1] * rsqrtf(p3[co + 1] + BN_EPS);
                h1 = p1[co + 1] - p2[co + 1] * s1;
            }
            unsigned* pp = outp + ((size_t)(b * 32 + (co >> 1))) * HW + px0;
#pragma unroll
            for (int nt = 0; nt < NT; ++nt) {
                float r0 = acc[nt][rg] * s0 + h0;
                float r1 = acc[nt][rg + 1] * s1 + h1;
                if (MODE == 1) { r0 = fmaxf(r0, 0.f); r1 = fmaxf(r1, 0.f); }
                pp[nt * 16 + lcol] = packbf(r0, r1);
            }
        }
    } else {
#pragma unroll
        for (int rg = 0; rg < 4; ++rg) {
            int co = wid * 16 + lrow * 4 + rg;
            float scale, shift;
            if (MODE == 0) { scale = 1.f; shift = p0[co]; }
            else {
                float inv = p0[co] * rsqrtf(p3[co] + BN_EPS);
                scale = inv; shift = p1[co] - p2[co] * inv;
            }
            float* op = out + ((size_t)(b * 64 + co)) * HW + px0;
#pragma unroll
            for (int nt = 0; nt < NT; ++nt) {
                float r = acc[nt][rg] * scale + shift;
                if (MODE == 1) r = fmaxf(r, 0.f);
                op[nt * 16 + lcol] = r;
            }
        }
    }
}

// standalone conv1x1 (comp layers, packed in/out), grid (HW/NPX, 1, B)
template<int C_IN, int NPX, int MODE, bool INPK, bool OUTMIR>
__global__ __launch_bounds__(256, 4)
void conv1x1_mfma(const float* __restrict__ x, const unsigned* __restrict__ xp,
                  const unsigned short* __restrict__ wb,
                  const float* __restrict__ p0, const float* __restrict__ p1,
                  const float* __restrict__ p2, const float* __restrict__ p3,
                  float* __restrict__ out, unsigned* __restrict__ outp, int HW)
{
    __shared__ __align__(16) unsigned short xs[4 * NPX * 8];
    int nb = HW / NPX;
    int f = blockIdx.x + nb * blockIdx.z;
    conv1x1_body<C_IN, NPX, MODE, INPK, OUTMIR>(f, xs, x, xp, wb, p0, p1, p2, p3, out, outp, HW);
}

// fused lateral convs (R21: KSPLIT=1 everywhere — reduce_multi deleted).
// lat0 [0,480) fp32; lat1 [480,600) fp32 (bias folded); lat2 [600,660)
// mirror-only (fp32 lat2 has no consumers anymore).
__global__ __launch_bounds__(256, 4)
void lat_multi(const float* __restrict__ x0, const unsigned short* __restrict__ w0,
               const float* __restrict__ b0, float* __restrict__ lat0,
               const float* __restrict__ x1, const unsigned short* __restrict__ w1,
               const float* __restrict__ b1, float* __restrict__ lat1,
               const float* __restrict__ x2, const unsigned short* __restrict__ w2,
               const float* __restrict__ b2, unsigned* __restrict__ lat2p)
{
    __shared__ __align__(16) unsigned short xs[4 * 128 * 8];
    int f = blockIdx.x;
    if (f < 480)
        conv1x1_body<128, 128, 0, false, false>(f, xs, x0, nullptr, w0,
            b0, nullptr, nullptr, nullptr, lat0, nullptr, 15360);
    else if (f < 600)
        conv1x1_body<256, 128, 0, false, false>(f - 480, xs, x1, nullptr, w1,
            b1, nullptr, nullptr, nullptr, lat1, nullptr, 3840);
    else
        conv1x1_body<512, 64, 0, false, true>(f - 600, xs, x2, nullptr, w2,
            b2, nullptr, nullptr, nullptr, nullptr, lat2p, 960);
}

// ---------------------------------------------------------------------------
// CARAFE v6: src read from bf16 pair-packed mirror (half the staging loads);
// dst = fp32 base (pre-CARAFE lateral) read + acc, write MIRROR ONLY (no
// remaining fp32 consumers).  bounds 4 (R4: 6 regressed).
// grid: (2w/16, 2h/16, B * CGS), block 256
// ---------------------------------------------------------------------------
template<int CGS>
__global__ __launch_bounds__(256, 4)
void carafe_kernel(const unsigned* __restrict__ srcp, const float* __restrict__ logits,
                   const float* __restrict__ base, unsigned* __restrict__ dstp,
                   int h, int w)
{
    constexpr int SW = 12, NPX = 144;
    constexpr int CH = 64 / CGS;     // 32
    constexpr int CP = CH / 2;       // 16 channel-pairs
    constexpr int CS = CH + 4;
    __shared__ float ls[NPX * CS];

    int tid = threadIdx.x;
    int x0 = blockIdx.x * 16, y0 = blockIdx.y * 16;
    int b  = blockIdx.z / CGS;
    int cs = blockIdx.z % CGS;
    int H = 2 * h, W = 2 * w;
    int xs0 = (x0 >> 1) - 2, ys0 = (y0 >> 1) - 2;
    size_t hw = (size_t)h * w;
    const unsigned* sb = srcp + ((size_t)(b * 32 + cs * CP)) * hw;

    for (int i = tid; i < NPX * CP; i += 256) {
        int cpl = i / NPX, p = i - cpl * NPX;
        int yy = p / SW, xx = p - yy * SW;
        int sy = ys0 + yy, sx = xs0 + xx;
        unsigned u = 0;
        if (sy >= 0 && sy < h && sx >= 0 && sx < w)
            u = sb[(size_t)cpl * hw + (size_t)sy * w + sx];
        ls[p * CS + 2 * cpl]     = __uint_as_float(u << 16);
        ls[p * CS + 2 * cpl + 1] = __uint_as_float(u & 0xffff0000u);
    }
    __syncthreads();

    int lx = tid & 15, ty = tid >> 4;
    int x = x0 + lx, y = y0 + ty;
    int xw = x >> 1, yh = y >> 1;
    int par = (y & 1) * 2 + (x & 1);

    const float* lp = logits + ((size_t)(b * 100 + par) * h + yh) * w + xw;
    float l[25];
    float mx = -1e30f;
#pragma unroll
    for (int k = 0; k < 25; ++k) {
        l[k] = lp[(size_t)(4 * k) * hw];
        mx = fmaxf(mx, l[k]);
    }
    float s = 0.f;
#pragma unroll
    for (int k = 0; k < 25; ++k) {
        l[k] = __expf(l[k] - mx);
        s += l[k];
    }
    float invs = 1.f / s;
#pragma unroll
    for (int k = 0; k < 25; ++k) l[k] *= invs;

    int pb = (yh - ys0 - 2) * SW + (xw - xs0 - 2);

#pragma unroll 1
    for (int cg = 0; cg < CH / 16; ++cg) {
        float acc[16];
#pragma unroll
        for (int c = 0; c < 16; ++c) acc[c] = 0.f;
#pragma unroll
        for (int k = 0; k < 25; ++k) {
            int ti = k / 5, tj = k - ti * 5;
            const float* q = &ls[(pb + ti * SW + tj) * CS + cg * 16];
            float wk = l[k];
#pragma unroll
            for (int c = 0; c < 16; ++c)
                acc[c] = fmaf(wk, q[c], acc[c]);
        }
        int cbase = cs * CH + cg * 16;
        const float* dp = base + (((size_t)(b * 64 + cbase)) * H + y) * W + x;
        unsigned* pp = dstp + (((size_t)(b * 32 + (cbase >> 1))) * H + y) * W + x;
#pragma unroll
        for (int c = 0; c < 16; c += 2) {
            float n0 = dp[(size_t)c * H * W] + acc[c];
            float n1 = dp[(size_t)(c + 1) * H * W] + acc[c + 1];
            pp[(size_t)(c >> 1) * H * W] = packbf(n0, n1);
        }
    }
}

// ---------------------------------------------------------------------------
extern "C" void kernel_launch(void* const* d_in, const int* in_sizes, int n_in,
                              void* d_out, int out_size, void* d_ws, size_t ws_size,
                              hipStream_t stream)
{
    const float* x0      = (const float*)d_in[0];
    const float* lat0_w  = (const float*)d_in[1];
    const float* lat0_b  = (const float*)d_in[2];
    const float* fpn0_w  = (const float*)d_in[3];
    const float* fpn0_b  = (const float*)d_in[4];
    const float* x1      = (const float*)d_in[5];
    const float* lat1_w  = (const float*)d_in[6];
    const float* lat1_b  = (const float*)d_in[7];
    const float* fpn1_w  = (const float*)d_in[8];
    const float* fpn1_b  = (const float*)d_in[9];
    const float* x2      = (const float*)d_in[10];
    const float* lat2_w  = (const float*)d_in[11];
    const float* lat2_b  = (const float*)d_in[12];
    const float* fpn2_w  = (const float*)d_in[13];
    const float* fpn2_b  = (const float*)d_in[14];
    const float* u0_comp_w = (const float*)d_in[15];
    const float* u0_enc_w  = (const float*)d_in[16];
    const float* u0_comp_g  = (const float*)d_in[17];
    const float* u0_comp_bt = (const float*)d_in[18];
    const float* u0_comp_m  = (const float*)d_in[19];
    const float* u0_comp_v  = (const float*)d_in[20];
    const float* u0_enc_g   = (const float*)d_in[21];
    const float* u0_enc_bt  = (const float*)d_in[22];
    const float* u0_enc_m   = (const float*)d_in[23];
    const float* u0_enc_v   = (const float*)d_in[24];
    const float* u1_comp_w = (const float*)d_in[25];
    const float* u1_enc_w  = (const float*)d_in[26];
    const float* u1_comp_g  = (const float*)d_in[27];
    const float* u1_comp_bt = (const float*)d_in[28];
    const float* u1_comp_m  = (const float*)d_in[29];
    const float* u1_comp_v  = (const float*)d_in[30];
    const float* u1_enc_g   = (const float*)d_in[31];
    const float* u1_enc_bt  = (const float*)d_in[32];
    const float* u1_enc_m   = (const float*)d_in[33];
    const float* u1_enc_v   = (const float*)d_in[34];

    float* out = (float*)d_out;
    const size_t OUT0 = 4ull * 64 * 96 * 160;   // 3,932,160
    const size_t OUT1 = 4ull * 64 * 48 * 80;    //   983,040
    const size_t OUT2 = 4ull * 64 * 24 * 40;    //   245,760
    float* out0 = out;
    float* out1 = out + OUT0;
    float* out2 = out + OUT0 + OUT1;

    float* lat0 = (float*)d_ws;
    float* lat1 = lat0 + OUT0;
    float* lat2 = lat1 + OUT1;                  // fp32 slot unused (kept for layout)
    unsigned short* wtb = (unsigned short*)(lat2 + OUT2);   // 239,616 bf16
    unsigned short* wt_fpn0 = wtb;
    unsigned short* wt_fpn1 = wtb + 36864;
    unsigned short* wt_fpn2 = wtb + 73728;
    unsigned short* wt_enc0 = wtb + 110592;
    unsigned short* wt_enc1 = wtb + 175104;
    unsigned short* wb = wtb + 239616;                      // 65,536 bf16 (1x1)
    unsigned short* wb_lat0  = wb;
    unsigned short* wb_lat1  = wb + 8192;
    unsigned short* wb_lat2  = wb + 24576;
    unsigned short* wb_comp0 = wb + 57344;
    unsigned short* wb_comp1 = wb + 61440;
    // bf16 channel-pair-packed mirrors ([b][cp=32][H][W] u32):
    unsigned* lat0p = (unsigned*)(wb + 65536);              // 1,966,080 u32
    unsigned* lat1p = lat0p + 1966080;                      //   491,520 u32
    unsigned* lat2p = lat1p + 491520;                       //   122,880 u32
    unsigned* compp = lat2p + 122880;                       //   491,520 u32 (max)
    // out0 region doubles as scratch (fpn0 overwrites it LAST):
    float* enc   = out0 + OUT1;          // enc logits

    dim3 blk(256);

    // 0) weight prep
    prep_weights<<<dim3(252, 10), blk, 0, stream>>>(
        fpn0_w, fpn1_w, fpn2_w, u0_enc_w, u1_enc_w, wtb,
        lat0_w, lat1_w, lat2_w, u0_comp_w, u1_comp_w, wb);

    // 1) all three lateral 1x1 convs, full-K, bias folded — ONE dispatch (660)
    lat_multi<<<dim3(660), blk, 0, stream>>>(
        x0, wb_lat0, lat0_b, lat0,
        x1, wb_lat1, lat1_b, lat1,
        x2, wb_lat2, lat2_b, lat2p);

    // 2) CARAFE u1: comp1 (packed in/out) -> enc1 + fpn2 backfill -> carafe1
    conv1x1_mfma<64, 32, 1, true, true><<<dim3(30, 1, 4), blk, 0, stream>>>(
        nullptr, lat2p, wb_comp1, u1_comp_g, u1_comp_bt, u1_comp_m, u1_comp_v,
        nullptr, compp, 24 * 40);
    enc_fpn<<<dim3(264), blk, 0, stream>>>(168,
        compp, wt_enc1, u1_enc_g, u1_enc_bt, u1_enc_m, u1_enc_v, enc, 24, 40, 3,
        lat2p, wt_fpn2, fpn2_b, out2, 24, 40, 3);
    carafe_kernel<2><<<dim3(5, 3, 8), blk, 0, stream>>>(lat2p, enc, lat1, lat1p, 24, 40);

    // 3) CARAFE u0: comp0 -> enc0 + fpn1 backfill -> carafe0
    conv1x1_mfma<64, 32, 1, true, true><<<dim3(120, 1, 4), blk, 0, stream>>>(
        nullptr, lat1p, wb_comp0, u0_comp_g, u0_comp_bt, u0_comp_m, u0_comp_v,
        nullptr, compp, 48 * 80);
    enc_fpn<<<dim3(660), blk, 0, stream>>>(420,
        compp, wt_enc0, u0_enc_g, u0_enc_bt, u0_enc_m, u0_enc_v, enc, 48, 80, 5,
        lat1p, wt_fpn1, fpn1_b, out1, 48, 80, 5);
    carafe_kernel<2><<<dim3(10, 6, 8), blk, 0, stream>>>(lat1p, enc, lat0, lat0p, 48, 80);

    // 4) final fpn: level0 only (960 blocks)
    fpn_multi<<<dim3(960), blk, 0, stream>>>(lat0p, wt_fpn0, fpn0_b, out0);
}

// Round 9
// 272.414 us; speedup vs baseline: 1.2821x; 1.0139x over previous
//
#include <hip/hip_runtime.h>

#define BN_EPS 1e-5f

typedef __attribute__((ext_vector_type(8))) short bf16x8;
typedef __attribute__((ext_vector_type(4))) float f32x4;

__device__ __forceinline__ unsigned short f2bf(float f) {
    unsigned u = __float_as_uint(f);
    return (unsigned short)((u + 0x7fffu + ((u >> 16) & 1u)) >> 16);   // RNE
}
__device__ __forceinline__ unsigned packbf(float lo, float hi) {
    return ((unsigned)f2bf(hi) << 16) | (unsigned)f2bf(lo);
}
__device__ __forceinline__ float bf2f(unsigned short u) {
    return __uint_as_float((unsigned)u << 16);
}
// load 8 consecutive fp32 weights, convert to bf16x8 in-register (R22: kills
// the prep dispatch for 1x1 weights — layout [co][ci] is already GEMM-ready)
__device__ __forceinline__ bf16x8 ldw8(const float* p) {
    float4 a = *(const float4*)p;
    float4 b = *(const float4*)(p + 4);
    union { unsigned u[4]; bf16x8 v; } r;
    r.u[0] = packbf(a.x, a.y);
    r.u[1] = packbf(a.z, a.w);
    r.u[2] = packbf(b.x, b.y);
    r.u[3] = packbf(b.z, b.w);
    return r.v;
}

// ---------------------------------------------------------------------------
// conv3x3 body (bf16 MFMA 16x16x32, C_in=64, fp32 acc).  LDS 20736 B.
// Split-K staging; PACKED mirror input [b][cp=32][H][W] u32.
// OBF16: epilogue writes bf16 (enc logits — carafe reads 2B/tap).
// CPB stays 1 (R1/R2 VGPR cliff).
// ---------------------------------------------------------------------------
template<int COP, int CSPLIT, int MODE, bool OBF16>
__device__ __forceinline__
void conv3x3_body(int rem, int TX, unsigned short* xs,
                  const unsigned* __restrict__ xp,
                  const unsigned short* __restrict__ wt,
                  const float* __restrict__ p0, const float* __restrict__ p1,
                  const float* __restrict__ p2, const float* __restrict__ p3,
                  float* __restrict__ out, unsigned short* __restrict__ out_us,
                  int H, int W, int C_out)
{
    constexpr int NP = 324;
    constexpr int CT = COP / 16;
    static_assert(CT == CSPLIT, "CPB must be 1 (R1/R2 VGPR cliff)");

    int cs = rem % CSPLIT;
    int b  = (rem / CSPLIT) & 3;
    int t  = rem / (CSPLIT * 4);
    int x0 = (t % TX) * 16, y0 = (t / TX) * 16;

    int tid  = threadIdx.x;
    int lane = tid & 63, wid = tid >> 6;
    int lrow = lane >> 4, lcol = lane & 15;
    int HWp = H * W;

    int co0 = cs * 16;
    bool colok = (x0 + lcol) < W;

    f32x4 accA[2], accB[2];
#pragma unroll
    for (int rr = 0; rr < 2; ++rr) {
        accA[rr] = (f32x4){0.f, 0.f, 0.f, 0.f};
        accB[rr] = (f32x4){0.f, 0.f, 0.f, 0.f};
    }

    unsigned int* wsl = (unsigned int*)xs;

#pragma unroll 1
    for (int kb = 0; kb < 2; ++kb) {
        if (kb) __syncthreads();          // protect xs before overwrite
        // ---- stage ch-pairs [kb*16, kb*16+16) of the 18x18 halo tile ----
        for (int p = tid; p < NP; p += 256) {
            int py = p / 18, px = p - py * 18;
            int gy = y0 + py - 1, gx = x0 + px - 1;
            bool ok = (gy >= 0) && (gy < H) && (gx >= 0) && (gx < W);
            const unsigned* gpp = xp + ((size_t)b * 32 + kb * 16) * HWp
                                     + (size_t)gy * W + gx;
#pragma unroll 8
            for (int cp = 0; cp < 16; ++cp) {
                unsigned pk = ok ? gpp[(size_t)cp * HWp] : 0u;
                wsl[((cp >> 2) * NP + p) * 4 + (cp & 3)] = pk;
            }
        }
        __syncthreads();

        // ---- weights for this K-half: 9 taps x 1 frag ----
        bf16x8 a[9];
        const unsigned short* wl = wt + ((size_t)co0 + lcol) * 64 + kb * 32 + lrow * 8;
#pragma unroll
        for (int t9 = 0; t9 < 9; ++t9)
            a[t9] = *(const bf16x8*)(wl + (size_t)t9 * COP * 64);

        // ---- 18 MFMAs into persistent accumulators ----
#pragma unroll
        for (int rr = 0; rr < 2; ++rr) {
            int r0 = wid + rr * 8;
#pragma unroll
            for (int t9 = 0; t9 < 9; ++t9) {
                int dy = t9 / 3, dx = t9 - dy * 3;
                int g0 = lrow * NP + (r0 + dy) * 18 + lcol + dx;
                bf16x8 b0 = *(const bf16x8*)(xs + (size_t)g0 * 8);
                accA[rr] = __builtin_amdgcn_mfma_f32_16x16x32_bf16(a[t9], b0, accA[rr], 0, 0, 0);
                bf16x8 b1 = *(const bf16x8*)(xs + ((size_t)g0 + 4 * 18) * 8);
                accB[rr] = __builtin_amdgcn_mfma_f32_16x16x32_bf16(a[t9], b1, accB[rr], 0, 0, 0);
            }
        }
    }

    // ---- epilogue: BN/bias + store ----
    float sc[4], sh[4];
#pragma unroll
    for (int rg = 0; rg < 4; ++rg) {
        int co = co0 + lrow * 4 + rg;
        int cc = (co < C_out) ? co : 0;
        if (MODE == 0) { sc[rg] = 1.f; sh[rg] = p0[cc]; }
        else {
            float inv = p0[cc] * rsqrtf(p3[cc] + BN_EPS);
            sc[rg] = inv; sh[rg] = p1[cc] - p2[cc] * inv;
        }
    }
#pragma unroll
    for (int rr = 0; rr < 2; ++rr) {
        int r0 = wid + rr * 8;
        int yA = y0 + r0, yB = y0 + r0 + 4;
#pragma unroll
        for (int rg = 0; rg < 4; ++rg) {
            int co = co0 + lrow * 4 + rg;
            if (colok && co < C_out) {
                float vA = accA[rr][rg] * sc[rg] + sh[rg];
                float vB = accB[rr][rg] * sc[rg] + sh[rg];
                if (OBF16) {
                    unsigned short* oc = out_us + (((size_t)b * C_out + co) * H) * W + x0 + lcol;
                    if (yA < H) oc[(size_t)yA * W] = f2bf(vA);
                    if (yB < H) oc[(size_t)yB * W] = f2bf(vB);
                } else {
                    float* oc = out + (((size_t)b * C_out + co) * H) * W + x0 + lcol;
                    if (yA < H) oc[(size_t)yA * W] = vA;
                    if (yB < H) oc[(size_t)yB * W] = vB;
                }
            }
        }
    }
}

// enc conv3x3 (PACKED in, bf16 out) + independent fpn level in ONE dispatch.
__global__ __launch_bounds__(256, 6)
void enc_fpn(int encBlocks,
             const unsigned* __restrict__ cxp, const unsigned short* __restrict__ wt_e,
             const float* __restrict__ g, const float* __restrict__ bt,
             const float* __restrict__ m, const float* __restrict__ v,
             unsigned short* __restrict__ enc_us, int He, int We, int TXe,
             const unsigned* __restrict__ xp, const unsigned short* __restrict__ wt_f,
             const float* __restrict__ bias, float* __restrict__ fout,
             int Hf, int Wf, int TXf)
{
    __shared__ unsigned short xs[4 * 324 * 8];
    int f = blockIdx.x;
    if (f < encBlocks)
        conv3x3_body<112, 7, 1, true>(f, TXe, xs, cxp, wt_e,
                                      g, bt, m, v, nullptr, enc_us, He, We, 100);
    else
        conv3x3_body<64, 4, 0, false>(f - encBlocks, TXf, xs, xp, wt_f,
                                      bias, nullptr, nullptr, nullptr, fout, nullptr, Hf, Wf, 64);
}

// final fpn: level0 only.  grid (960)
__global__ __launch_bounds__(256, 6)
void fpn_multi(const unsigned* __restrict__ l0p, const unsigned short* __restrict__ wt0,
               const float* __restrict__ b0, float* __restrict__ o0)
{
    __shared__ unsigned short xs[4 * 324 * 8];
    conv3x3_body<64, 4, 0, false>(blockIdx.x, 10, xs, l0p, wt0,
                                  b0, nullptr, nullptr, nullptr, o0, nullptr, 96, 160, 64);
}

// ---------------------------------------------------------------------------
// conv1x1 body (bf16 MFMA GEMM).  R22: fp32 weights converted in-register
// (ldw8 — prep dispatch deleted); output ALWAYS bf16 pair-packed mirror.
// INPK: input is packed mirror (uint4 staging).
// ---------------------------------------------------------------------------
template<int C_IN, int NPX, int MODE, bool INPK>
__device__ __forceinline__
void conv1x1_body(int f, unsigned short* xs,
                  const float* __restrict__ x, const unsigned* __restrict__ xp,
                  const float* __restrict__ wf,
                  const float* __restrict__ p0, const float* __restrict__ p1,
                  const float* __restrict__ p2, const float* __restrict__ p3,
                  unsigned* __restrict__ outp, int HW)
{
    constexpr int NT = NPX / 16;
    constexpr int QUADS = NPX / 4;          // pow2
    int nb = HW / NPX;
    int px0 = (f % nb) * NPX;
    int b   = f / nb;

    int tid = threadIdx.x;
    int lane = tid & 63, wid = tid >> 6;
    int lrow = lane >> 4, lcol = lane & 15;
    const float*    xb  = INPK ? nullptr : x + (size_t)b * C_IN * HW + px0;
    const unsigned* xpb = INPK ? xp + (size_t)b * (C_IN / 2) * HW + px0 : nullptr;

    f32x4 acc[NT];
#pragma unroll
    for (int nt = 0; nt < NT; ++nt) acc[nt] = (f32x4){0.f, 0.f, 0.f, 0.f};

    for (int cc = 0; cc < C_IN; cc += 32) {
        if (cc) __syncthreads();
        for (int j = tid; j < 16 * QUADS; j += 256) {
            int q  = j & (QUADS - 1);
            int cp = j / QUADS;
            int px = q * 4;
            unsigned* wv = (unsigned*)xs + ((size_t)(cp >> 2) * NPX + px) * 4 + (cp & 3);
            if (INPK) {
                uint4 v = *(const uint4*)(xpb + (size_t)(cc / 2 + cp) * HW + px);
                wv[0] = v.x; wv[4] = v.y; wv[8] = v.z; wv[12] = v.w;
            } else {
                const float* s0 = xb + (size_t)(cc + 2 * cp) * HW + px;
                float4 v0 = *(const float4*)s0;
                float4 v1 = *(const float4*)(s0 + HW);
                wv[0]  = packbf(v0.x, v1.x);
                wv[4]  = packbf(v0.y, v1.y);
                wv[8]  = packbf(v0.z, v1.z);
                wv[12] = packbf(v0.w, v1.w);
            }
        }
        __syncthreads();

        bf16x8 a = ldw8(wf + (size_t)(wid * 16 + lcol) * C_IN + cc + lrow * 8);
#pragma unroll
        for (int nt = 0; nt < NT; ++nt) {
            bf16x8 bf = *(const bf16x8*)(xs + ((size_t)lrow * NPX + nt * 16 + lcol) * 8);
            acc[nt] = __builtin_amdgcn_mfma_f32_16x16x32_bf16(a, bf, acc[nt], 0, 0, 0);
        }
    }

#pragma unroll
    for (int rg = 0; rg < 4; rg += 2) {
        int co = wid * 16 + lrow * 4 + rg;
        float s0, h0, s1, h1;
        if (MODE == 0) { s0 = 1.f; h0 = p0[co]; s1 = 1.f; h1 = p0[co + 1]; }
        else {
            s0 = p0[co] * rsqrtf(p3[co] + BN_EPS);
            h0 = p1[co] - p2[co] * s0;
            s1 = p0[co + 1] * rsqrtf(p3[co + 1] + BN_EPS);
            h1 = p1[co + 1] - p2[co + 1] * s1;
        }
        unsigned* pp = outp + ((size_t)(b * 32 + (co >> 1))) * HW + px0;
#pragma unroll
        for (int nt = 0; nt < NT; ++nt) {
            float r0 = acc[nt][rg] * s0 + h0;
            float r1 = acc[nt][rg + 1] * s1 + h1;
            if (MODE == 1) { r0 = fmaxf(r0, 0.f); r1 = fmaxf(r1, 0.f); }
            pp[nt * 16 + lcol] = packbf(r0, r1);
        }
    }
}

// standalone conv1x1 (comp layers, packed in, fp32 weights), grid (HW/NPX,1,B)
template<int C_IN, int NPX, int MODE, bool INPK>
__global__ __launch_bounds__(256, 4)
void conv1x1_mfma(const float* __restrict__ x, const unsigned* __restrict__ xp,
                  const float* __restrict__ wf,
                  const float* __restrict__ p0, const float* __restrict__ p1,
                  const float* __restrict__ p2, const float* __restrict__ p3,
                  unsigned* __restrict__ outp, int HW)
{
    __shared__ __align__(16) unsigned short xs[4 * NPX * 8];
    int nb = HW / NPX;
    int f = blockIdx.x + nb * blockIdx.z;
    conv1x1_body<C_IN, NPX, MODE, INPK>(f, xs, x, xp, wf, p0, p1, p2, p3, outp, HW);
}

// R22: fused lateral convs + 3x3 weight prep backfill — ONE dispatch (894).
// lat0 [0,480) -> lat0b mirror; lat1 [480,600) -> lat1b mirror;
// lat2 [600,660) -> lat2p mirror; prep3x3 [660,894): 234*1024 = 239,616 elems.
__global__ __launch_bounds__(256, 4)
void lat_prep(const float* __restrict__ x0, const float* __restrict__ w0,
              const float* __restrict__ b0, unsigned* __restrict__ lat0b,
              const float* __restrict__ x1, const float* __restrict__ w1,
              const float* __restrict__ b1, unsigned* __restrict__ lat1b,
              const float* __restrict__ x2, const float* __restrict__ w2,
              const float* __restrict__ b2, unsigned* __restrict__ lat2p,
              const float* __restrict__ f0w, const float* __restrict__ f1w,
              const float* __restrict__ f2w, const float* __restrict__ e0w,
              const float* __restrict__ e1w, unsigned short* __restrict__ wtb)
{
    __shared__ __align__(16) unsigned short xs[4 * 128 * 8];
    int f = blockIdx.x;
    if (f < 480)
        conv1x1_body<128, 128, 0, false>(f, xs, x0, nullptr, w0,
            b0, nullptr, nullptr, nullptr, lat0b, 15360);
    else if (f < 600)
        conv1x1_body<256, 128, 0, false>(f - 480, xs, x1, nullptr, w1,
            b1, nullptr, nullptr, nullptr, lat1b, 3840);
    else if (f < 660)
        conv1x1_body<512, 64, 0, false>(f - 600, xs, x2, nullptr, w2,
            b2, nullptr, nullptr, nullptr, lat2p, 960);
    else {
        int base = (f - 660) * 1024 + threadIdx.x;
#pragma unroll
        for (int t = 0; t < 4; ++t) {
            int i = base + t * 256;            // < 239616 exactly
            float v;
            if (i < 110592) {
                int z = i / 36864;
                int rem = i - z * 36864;
                int tap = rem / 4096;          // 64*64
                int r2 = rem - tap * 4096;
                int co = r2 >> 6, ci = r2 & 63;
                const float* src = (z == 0) ? f0w : (z == 1 ? f1w : f2w);
                v = src[((size_t)co * 64 + ci) * 9 + tap];
            } else {
                int j = i - 110592;
                int z = j / 64512;
                int rem = j - z * 64512;
                int tap = rem / 7168;          // 112*64
                int r2 = rem - tap * 7168;
                int co = r2 >> 6, ci = r2 & 63;
                const float* src = z ? e1w : e0w;
                v = (co < 100) ? src[((size_t)co * 64 + ci) * 9 + tap] : 0.f;
            }
            wtb[i] = f2bf(v);
        }
    }
}

// ---------------------------------------------------------------------------
// CARAFE v7: src from packed mirror; logits bf16 (R22); base from packed
// mirror (R22); dst mirror only.  bounds 4 (R4: 6 regressed).
// grid: (2w/16, 2h/16, B * CGS), block 256
// ---------------------------------------------------------------------------
template<int CGS>
__global__ __launch_bounds__(256, 4)
void carafe_kernel(const unsigned* __restrict__ srcp,
                   const unsigned short* __restrict__ logits_us,
                   const unsigned* __restrict__ basep, unsigned* __restrict__ dstp,
                   int h, int w)
{
    constexpr int SW = 12, NPX = 144;
    constexpr int CH = 64 / CGS;     // 32
    constexpr int CP = CH / 2;       // 16 channel-pairs
    constexpr int CS = CH + 4;
    __shared__ float ls[NPX * CS];

    int tid = threadIdx.x;
    int x0 = blockIdx.x * 16, y0 = blockIdx.y * 16;
    int b  = blockIdx.z / CGS;
    int cs = blockIdx.z % CGS;
    int H = 2 * h, W = 2 * w;
    int xs0 = (x0 >> 1) - 2, ys0 = (y0 >> 1) - 2;
    size_t hw = (size_t)h * w;
    const unsigned* sb = srcp + ((size_t)(b * 32 + cs * CP)) * hw;

    for (int i = tid; i < NPX * CP; i += 256) {
        int cpl = i / NPX, p = i - cpl * NPX;
        int yy = p / SW, xx = p - yy * SW;
        int sy = ys0 + yy, sx = xs0 + xx;
        unsigned u = 0;
        if (sy >= 0 && sy < h && sx >= 0 && sx < w)
            u = sb[(size_t)cpl * hw + (size_t)sy * w + sx];
        ls[p * CS + 2 * cpl]     = __uint_as_float(u << 16);
        ls[p * CS + 2 * cpl + 1] = __uint_as_float(u & 0xffff0000u);
    }
    __syncthreads();

    int lx = tid & 15, ty = tid >> 4;
    int x = x0 + lx, y = y0 + ty;
    int xw = x >> 1, yh = y >> 1;
    int par = (y & 1) * 2 + (x & 1);

    const unsigned short* lp = logits_us + ((size_t)(b * 100 + par) * h + yh) * w + xw;
    float l[25];
    float mx = -1e30f;
#pragma unroll
    for (int k = 0; k < 25; ++k) {
        l[k] = bf2f(lp[(size_t)(4 * k) * hw]);
        mx = fmaxf(mx, l[k]);
    }
    float s = 0.f;
#pragma unroll
    for (int k = 0; k < 25; ++k) {
        l[k] = __expf(l[k] - mx);
        s += l[k];
    }
    float invs = 1.f / s;
#pragma unroll
    for (int k = 0; k < 25; ++k) l[k] *= invs;

    int pb = (yh - ys0 - 2) * SW + (xw - xs0 - 2);

#pragma unroll 1
    for (int cg = 0; cg < CH / 16; ++cg) {
        float acc[16];
#pragma unroll
        for (int c = 0; c < 16; ++c) acc[c] = 0.f;
#pragma unroll
        for (int k = 0; k < 25; ++k) {
            int ti = k / 5, tj = k - ti * 5;
            const float* q = &ls[(pb + ti * SW + tj) * CS + cg * 16];
            float wk = l[k];
#pragma unroll
            for (int c = 0; c < 16; ++c)
                acc[c] = fmaf(wk, q[c], acc[c]);
        }
        int cbase = cs * CH + cg * 16;
        size_t poff = (((size_t)(b * 32 + (cbase >> 1))) * H + y) * W + x;
        const unsigned* bp = basep + poff;
        unsigned* pp = dstp + poff;
#pragma unroll
        for (int c = 0; c < 16; c += 2) {
            unsigned ub = bp[(size_t)(c >> 1) * H * W];
            float n0 = __uint_as_float(ub << 16) + acc[c];
            float n1 = __uint_as_float(ub & 0xffff0000u) + acc[c + 1];
            pp[(size_t)(c >> 1) * H * W] = packbf(n0, n1);
        }
    }
}

// ---------------------------------------------------------------------------
extern "C" void kernel_launch(void* const* d_in, const int* in_sizes, int n_in,
                              void* d_out, int out_size, void* d_ws, size_t ws_size,
                              hipStream_t stream)
{
    const float* x0      = (const float*)d_in[0];
    const float* lat0_w  = (const float*)d_in[1];
    const float* lat0_b  = (const float*)d_in[2];
    const float* fpn0_w  = (const float*)d_in[3];
    const float* fpn0_b  = (const float*)d_in[4];
    const float* x1      = (const float*)d_in[5];
    const float* lat1_w  = (const float*)d_in[6];
    const float* lat1_b  = (const float*)d_in[7];
    const float* fpn1_w  = (const float*)d_in[8];
    const float* fpn1_b  = (const float*)d_in[9];
    const float* x2      = (const float*)d_in[10];
    const float* lat2_w  = (const float*)d_in[11];
    const float* lat2_b  = (const float*)d_in[12];
    const float* fpn2_w  = (const float*)d_in[13];
    const float* fpn2_b  = (const float*)d_in[14];
    const float* u0_comp_w = (const float*)d_in[15];
    const float* u0_enc_w  = (const float*)d_in[16];
    const float* u0_comp_g  = (const float*)d_in[17];
    const float* u0_comp_bt = (const float*)d_in[18];
    const float* u0_comp_m  = (const float*)d_in[19];
    const float* u0_comp_v  = (const float*)d_in[20];
    const float* u0_enc_g   = (const float*)d_in[21];
    const float* u0_enc_bt  = (const float*)d_in[22];
    const float* u0_enc_m   = (const float*)d_in[23];
    const float* u0_enc_v   = (const float*)d_in[24];
    const float* u1_comp_w = (const float*)d_in[25];
    const float* u1_enc_w  = (const float*)d_in[26];
    const float* u1_comp_g  = (const float*)d_in[27];
    const float* u1_comp_bt = (const float*)d_in[28];
    const float* u1_comp_m  = (const float*)d_in[29];
    const float* u1_comp_v  = (const float*)d_in[30];
    const float* u1_enc_g   = (const float*)d_in[31];
    const float* u1_enc_bt  = (const float*)d_in[32];
    const float* u1_enc_m   = (const float*)d_in[33];
    const float* u1_enc_v   = (const float*)d_in[34];

    float* out = (float*)d_out;
    const size_t OUT0 = 4ull * 64 * 96 * 160;   // 3,932,160
    const size_t OUT1 = 4ull * 64 * 48 * 80;    //   983,040
    const size_t OUT2 = 4ull * 64 * 24 * 40;    //   245,760
    float* out0 = out;
    float* out1 = out + OUT0;
    float* out2 = out + OUT0 + OUT1;

    // workspace layout (all mirrors [b][cp=32][H][W] u32):
    unsigned* lat0b = (unsigned*)d_ws;                      // 1,966,080 u32
    unsigned* lat1b = lat0b + 1966080;                      //   491,520 u32
    unsigned short* wtb = (unsigned short*)(lat1b + 491520); // 239,616 bf16
    unsigned short* wt_fpn0 = wtb;
    unsigned short* wt_fpn1 = wtb + 36864;
    unsigned short* wt_fpn2 = wtb + 73728;
    unsigned short* wt_enc0 = wtb + 110592;
    unsigned short* wt_enc1 = wtb + 175104;
    unsigned* lat0p = (unsigned*)(wtb + 239616);            // 1,966,080 u32
    unsigned* lat1p = lat0p + 1966080;                      //   491,520 u32
    unsigned* lat2p = lat1p + 491520;                       //   122,880 u32
    unsigned* compp = lat2p + 122880;                       //   491,520 u32 (max)
    // out0 region doubles as scratch (fpn0 overwrites it LAST):
    unsigned short* enc_us = (unsigned short*)(out0 + OUT1); // enc logits bf16

    dim3 blk(256);

    // 1) laterals (full-K, bias folded, mirror out) + 3x3 weight prep backfill
    lat_prep<<<dim3(894), blk, 0, stream>>>(
        x0, lat0_w, lat0_b, lat0b,
        x1, lat1_w, lat1_b, lat1b,
        x2, lat2_w, lat2_b, lat2p,
        fpn0_w, fpn1_w, fpn2_w, u0_enc_w, u1_enc_w, wtb);

    // 2) CARAFE u1: comp1 -> enc1(bf16) + fpn2 backfill -> carafe1
    conv1x1_mfma<64, 32, 1, true><<<dim3(30, 1, 4), blk, 0, stream>>>(
        nullptr, lat2p, u1_comp_w, u1_comp_g, u1_comp_bt, u1_comp_m, u1_comp_v,
        compp, 24 * 40);
    enc_fpn<<<dim3(264), blk, 0, stream>>>(168,
        compp, wt_enc1, u1_enc_g, u1_enc_bt, u1_enc_m, u1_enc_v, enc_us, 24, 40, 3,
        lat2p, wt_fpn2, fpn2_b, out2, 24, 40, 3);
    carafe_kernel<2><<<dim3(5, 3, 8), blk, 0, stream>>>(lat2p, enc_us, lat1b, lat1p, 24, 40);

    // 3) CARAFE u0: comp0 -> enc0(bf16) + fpn1 backfill -> carafe0
    conv1x1_mfma<64, 32, 1, true><<<dim3(120, 1, 4), blk, 0, stream>>>(
        nullptr, lat1p, u0_comp_w, u0_comp_g, u0_comp_bt, u0_comp_m, u0_comp_v,
        compp, 48 * 80);
    enc_fpn<<<dim3(660), blk, 0, stream>>>(420,
        compp, wt_enc0, u0_enc_g, u0_enc_bt, u0_enc_m, u0_enc_v, enc_us, 48, 80, 5,
        lat1p, wt_fpn1, fpn1_b, out1, 48, 80, 5);
    carafe_kernel<2><<<dim3(10, 6, 8), blk, 0, stream>>>(lat1p, enc_us, lat0b, lat0p, 48, 80);

    // 4) final fpn: level0 only (960 blocks)
    fpn_multi<<<dim3(960), blk, 0, stream>>>(lat0p, wt_fpn0, fpn0_b, out0);
}

// Round 10
// 248.663 us; speedup vs baseline: 1.4046x; 1.0955x over previous
//
#include <hip/hip_runtime.h>

#define BN_EPS 1e-5f

typedef __attribute__((ext_vector_type(8))) short bf16x8;
typedef __attribute__((ext_vector_type(4))) float f32x4;

__device__ __forceinline__ unsigned short f2bf(float f) {
    unsigned u = __float_as_uint(f);
    return (unsigned short)((u + 0x7fffu + ((u >> 16) & 1u)) >> 16);   // RNE
}
__device__ __forceinline__ unsigned packbf(float lo, float hi) {
    return ((unsigned)f2bf(hi) << 16) | (unsigned)f2bf(lo);
}
__device__ __forceinline__ float bf2f(unsigned short u) {
    return __uint_as_float((unsigned)u << 16);
}
// load 8 consecutive fp32 weights, convert to bf16x8 in-register
__device__ __forceinline__ bf16x8 ldw8(const float* p) {
    float4 a = *(const float4*)p;
    float4 b = *(const float4*)(p + 4);
    union { unsigned u[4]; bf16x8 v; } r;
    r.u[0] = packbf(a.x, a.y);
    r.u[1] = packbf(a.z, a.w);
    r.u[2] = packbf(b.x, b.y);
    r.u[3] = packbf(b.z, b.w);
    return r.v;
}

// ---------------------------------------------------------------------------
// R23: mirrors are CHANNEL-LAST: [b][H][W][cp=32] u32 (cp k = channels 2k,2k+1
// pair-packed bf16).  One pixel = 128 contiguous bytes -> staging is uint4
// fully-coalesced loads + ds_write_b128 (the LDS dwords ((g*NP+p)*4+0..3) are
// consecutive for a uint4 of pairs 4g..4g+3).  enc logits channel-last
// [b][h][w][100] ushort (carafe's 25 taps: 2 lines instead of 25).
// ---------------------------------------------------------------------------

// ---------------------------------------------------------------------------
// conv3x3 body (bf16 MFMA 16x16x32, C_in=64, fp32 acc).  LDS 20736 B.
// Split-K staging; channel-last packed input.  OBF16: enc-logit bf16
// channel-last output.  CPB stays 1 (R1/R2 VGPR cliff).
// ---------------------------------------------------------------------------
template<int COP, int CSPLIT, int MODE, bool OBF16>
__device__ __forceinline__
void conv3x3_body(int rem, int TX, unsigned short* xs,
                  const unsigned* __restrict__ xp,
                  const unsigned short* __restrict__ wt,
                  const float* __restrict__ p0, const float* __restrict__ p1,
                  const float* __restrict__ p2, const float* __restrict__ p3,
                  float* __restrict__ out, unsigned short* __restrict__ out_us,
                  int H, int W, int C_out)
{
    constexpr int NP = 324;
    constexpr int CT = COP / 16;
    static_assert(CT == CSPLIT, "CPB must be 1 (R1/R2 VGPR cliff)");

    int cs = rem % CSPLIT;
    int b  = (rem / CSPLIT) & 3;
    int t  = rem / (CSPLIT * 4);
    int x0 = (t % TX) * 16, y0 = (t / TX) * 16;

    int tid  = threadIdx.x;
    int lane = tid & 63, wid = tid >> 6;
    int lrow = lane >> 4, lcol = lane & 15;
    int HWp = H * W;

    int co0 = cs * 16;
    bool colok = (x0 + lcol) < W;

    f32x4 accA[2], accB[2];
#pragma unroll
    for (int rr = 0; rr < 2; ++rr) {
        accA[rr] = (f32x4){0.f, 0.f, 0.f, 0.f};
        accB[rr] = (f32x4){0.f, 0.f, 0.f, 0.f};
    }

    unsigned int* wsl = (unsigned int*)xs;
    const unsigned* xb = xp + (size_t)b * HWp * 32;

#pragma unroll 1
    for (int kb = 0; kb < 2; ++kb) {
        if (kb) __syncthreads();          // protect xs before overwrite
        // ---- stage ch-pairs [kb*16, kb*16+16) of the 18x18 halo tile ----
        // item = (p, g): uint4 of pairs 4g..4g+3 at halo pixel p.
        for (int it = tid; it < NP * 4; it += 256) {
            int p = it >> 2, g = it & 3;
            int py = p / 18, px = p - py * 18;
            int gy = y0 + py - 1, gx = x0 + px - 1;
            uint4 v = make_uint4(0u, 0u, 0u, 0u);
            if (gy >= 0 && gy < H && gx >= 0 && gx < W)
                v = *(const uint4*)(xb + ((size_t)gy * W + gx) * 32 + kb * 16 + g * 4);
            *(uint4*)(wsl + ((size_t)g * NP + p) * 4) = v;
        }
        __syncthreads();

        // ---- weights for this K-half: 9 taps x 1 frag ----
        bf16x8 a[9];
        const unsigned short* wl = wt + ((size_t)co0 + lcol) * 64 + kb * 32 + lrow * 8;
#pragma unroll
        for (int t9 = 0; t9 < 9; ++t9)
            a[t9] = *(const bf16x8*)(wl + (size_t)t9 * COP * 64);

        // ---- 18 MFMAs into persistent accumulators ----
#pragma unroll
        for (int rr = 0; rr < 2; ++rr) {
            int r0 = wid + rr * 8;
#pragma unroll
            for (int t9 = 0; t9 < 9; ++t9) {
                int dy = t9 / 3, dx = t9 - dy * 3;
                int g0 = lrow * NP + (r0 + dy) * 18 + lcol + dx;
                bf16x8 b0 = *(const bf16x8*)(xs + (size_t)g0 * 8);
                accA[rr] = __builtin_amdgcn_mfma_f32_16x16x32_bf16(a[t9], b0, accA[rr], 0, 0, 0);
                bf16x8 b1 = *(const bf16x8*)(xs + ((size_t)g0 + 4 * 18) * 8);
                accB[rr] = __builtin_amdgcn_mfma_f32_16x16x32_bf16(a[t9], b1, accB[rr], 0, 0, 0);
            }
        }
    }

    // ---- epilogue: BN/bias + store ----
    float sc[4], sh[4];
#pragma unroll
    for (int rg = 0; rg < 4; ++rg) {
        int co = co0 + lrow * 4 + rg;
        int cc = (co < C_out) ? co : 0;
        if (MODE == 0) { sc[rg] = 1.f; sh[rg] = p0[cc]; }
        else {
            float inv = p0[cc] * rsqrtf(p3[cc] + BN_EPS);
            sc[rg] = inv; sh[rg] = p1[cc] - p2[cc] * inv;
        }
    }
#pragma unroll
    for (int rr = 0; rr < 2; ++rr) {
        int r0 = wid + rr * 8;
        int yA = y0 + r0, yB = y0 + r0 + 4;
        if (OBF16) {
            if (colok) {
                if (yA < H) {
                    unsigned short* oc = out_us + (((size_t)b * H + yA) * W + x0 + lcol) * 100;
#pragma unroll
                    for (int rg = 0; rg < 4; ++rg) {
                        int co = co0 + lrow * 4 + rg;
                        if (co < C_out) oc[co] = f2bf(accA[rr][rg] * sc[rg] + sh[rg]);
                    }
                }
                if (yB < H) {
                    unsigned short* oc = out_us + (((size_t)b * H + yB) * W + x0 + lcol) * 100;
#pragma unroll
                    for (int rg = 0; rg < 4; ++rg) {
                        int co = co0 + lrow * 4 + rg;
                        if (co < C_out) oc[co] = f2bf(accB[rr][rg] * sc[rg] + sh[rg]);
                    }
                }
            }
        } else {
#pragma unroll
            for (int rg = 0; rg < 4; ++rg) {
                int co = co0 + lrow * 4 + rg;
                if (colok && co < C_out) {
                    float* oc = out + (((size_t)b * C_out + co) * H) * W + x0 + lcol;
                    if (yA < H) oc[(size_t)yA * W] = accA[rr][rg] * sc[rg] + sh[rg];
                    if (yB < H) oc[(size_t)yB * W] = accB[rr][rg] * sc[rg] + sh[rg];
                }
            }
        }
    }
}

// enc conv3x3 (channel-last packed in, bf16 channel-last out) + independent
// fpn level in ONE dispatch.
__global__ __launch_bounds__(256, 6)
void enc_fpn(int encBlocks,
             const unsigned* __restrict__ cxp, const unsigned short* __restrict__ wt_e,
             const float* __restrict__ g, const float* __restrict__ bt,
             const float* __restrict__ m, const float* __restrict__ v,
             unsigned short* __restrict__ enc_us, int He, int We, int TXe,
             const unsigned* __restrict__ xp, const unsigned short* __restrict__ wt_f,
             const float* __restrict__ bias, float* __restrict__ fout,
             int Hf, int Wf, int TXf)
{
    __shared__ unsigned short xs[4 * 324 * 8];
    int f = blockIdx.x;
    if (f < encBlocks)
        conv3x3_body<112, 7, 1, true>(f, TXe, xs, cxp, wt_e,
                                      g, bt, m, v, nullptr, enc_us, He, We, 100);
    else
        conv3x3_body<64, 4, 0, false>(f - encBlocks, TXf, xs, xp, wt_f,
                                      bias, nullptr, nullptr, nullptr, fout, nullptr, Hf, Wf, 64);
}

// final fpn: level0 only.  grid (960)
__global__ __launch_bounds__(256, 6)
void fpn_multi(const unsigned* __restrict__ l0p, const unsigned short* __restrict__ wt0,
               const float* __restrict__ b0, float* __restrict__ o0)
{
    __shared__ unsigned short xs[4 * 324 * 8];
    conv3x3_body<64, 4, 0, false>(blockIdx.x, 10, xs, l0p, wt0,
                                  b0, nullptr, nullptr, nullptr, o0, nullptr, 96, 160, 64);
}

// ---------------------------------------------------------------------------
// conv1x1 body (bf16 MFMA GEMM).  fp32 weights converted in-register (ldw8);
// output: channel-last bf16 pair-packed mirror.  INPK: channel-last packed
// input (uint4 staging -> ds_write_b128).
// ---------------------------------------------------------------------------
template<int C_IN, int NPX, int MODE, bool INPK>
__device__ __forceinline__
void conv1x1_body(int f, unsigned short* xs,
                  const float* __restrict__ x, const unsigned* __restrict__ xp,
                  const float* __restrict__ wf,
                  const float* __restrict__ p0, const float* __restrict__ p1,
                  const float* __restrict__ p2, const float* __restrict__ p3,
                  unsigned* __restrict__ outp, int HW)
{
    constexpr int NT = NPX / 16;
    constexpr int QUADS = NPX / 4;          // pow2
    int nb = HW / NPX;
    int px0 = (f % nb) * NPX;
    int b   = f / nb;

    int tid = threadIdx.x;
    int lane = tid & 63, wid = tid >> 6;
    int lrow = lane >> 4, lcol = lane & 15;
    const float*    xb  = INPK ? nullptr : x + (size_t)b * C_IN * HW + px0;
    const unsigned* xpb = INPK ? xp + ((size_t)b * HW + px0) * 32 : nullptr;

    f32x4 acc[NT];
#pragma unroll
    for (int nt = 0; nt < NT; ++nt) acc[nt] = (f32x4){0.f, 0.f, 0.f, 0.f};

    for (int cc = 0; cc < C_IN; cc += 32) {
        if (cc) __syncthreads();
        if (INPK) {
            // item = (px, g): uint4 of pairs cc/2+4g..+3 at pixel px.
            for (int it = tid; it < NPX * 4; it += 256) {
                int px = it >> 2, g = it & 3;
                uint4 v = *(const uint4*)(xpb + (size_t)px * 32 + cc / 2 + g * 4);
                *(uint4*)((unsigned*)xs + ((size_t)g * NPX + px) * 4) = v;
            }
        } else {
            for (int j = tid; j < 16 * QUADS; j += 256) {
                int q  = j & (QUADS - 1);
                int cp = j / QUADS;
                int px = q * 4;
                const float* s0 = xb + (size_t)(cc + 2 * cp) * HW + px;
                float4 v0 = *(const float4*)s0;
                float4 v1 = *(const float4*)(s0 + HW);
                unsigned* wv = (unsigned*)xs + ((size_t)(cp >> 2) * NPX + px) * 4 + (cp & 3);
                wv[0]  = packbf(v0.x, v1.x);
                wv[4]  = packbf(v0.y, v1.y);
                wv[8]  = packbf(v0.z, v1.z);
                wv[12] = packbf(v0.w, v1.w);
            }
        }
        __syncthreads();

        bf16x8 a = ldw8(wf + (size_t)(wid * 16 + lcol) * C_IN + cc + lrow * 8);
#pragma unroll
        for (int nt = 0; nt < NT; ++nt) {
            bf16x8 bf = *(const bf16x8*)(xs + ((size_t)lrow * NPX + nt * 16 + lcol) * 8);
            acc[nt] = __builtin_amdgcn_mfma_f32_16x16x32_bf16(a, bf, acc[nt], 0, 0, 0);
        }
    }

    // epilogue: channel-last mirror write — thread owns 4 consecutive co
    // (= 2 consecutive pairs) at pixel nt*16+lcol -> one uint2 per nt.
    float sc[4], sh[4];
#pragma unroll
    for (int rg = 0; rg < 4; ++rg) {
        int co = wid * 16 + lrow * 4 + rg;
        if (MODE == 0) { sc[rg] = 1.f; sh[rg] = p0[co]; }
        else {
            float inv = p0[co] * rsqrtf(p3[co] + BN_EPS);
            sc[rg] = inv; sh[rg] = p1[co] - p2[co] * inv;
        }
    }
    unsigned* pp = outp + ((size_t)b * HW + px0) * 32 + wid * 8 + lrow * 2;
#pragma unroll
    for (int nt = 0; nt < NT; ++nt) {
        float r[4];
#pragma unroll
        for (int rg = 0; rg < 4; ++rg) {
            r[rg] = acc[nt][rg] * sc[rg] + sh[rg];
            if (MODE == 1) r[rg] = fmaxf(r[rg], 0.f);
        }
        uint2 pk = make_uint2(packbf(r[0], r[1]), packbf(r[2], r[3]));
        *(uint2*)(pp + (size_t)(nt * 16 + lcol) * 32) = pk;
    }
}

// standalone conv1x1 (comp layers, channel-last packed in), grid (HW/NPX,1,B)
template<int C_IN, int NPX, int MODE, bool INPK>
__global__ __launch_bounds__(256, 4)
void conv1x1_mfma(const float* __restrict__ x, const unsigned* __restrict__ xp,
                  const float* __restrict__ wf,
                  const float* __restrict__ p0, const float* __restrict__ p1,
                  const float* __restrict__ p2, const float* __restrict__ p3,
                  unsigned* __restrict__ outp, int HW)
{
    __shared__ __align__(16) unsigned short xs[4 * NPX * 8];
    int nb = HW / NPX;
    int f = blockIdx.x + nb * blockIdx.z;
    conv1x1_body<C_IN, NPX, MODE, INPK>(f, xs, x, xp, wf, p0, p1, p2, p3, outp, HW);
}

// fused lateral convs + 3x3 weight prep backfill — ONE dispatch (894).
// lat0 [0,480) -> lat0b; lat1 [480,600) -> lat1b; lat2 [600,660) -> lat2p;
// prep3x3 [660,894): 234*1024 = 239,616 elems.
__global__ __launch_bounds__(256, 4)
void lat_prep(const float* __restrict__ x0, const float* __restrict__ w0,
              const float* __restrict__ b0, unsigned* __restrict__ lat0b,
              const float* __restrict__ x1, const float* __restrict__ w1,
              const float* __restrict__ b1, unsigned* __restrict__ lat1b,
              const float* __restrict__ x2, const float* __restrict__ w2,
              const float* __restrict__ b2, unsigned* __restrict__ lat2p,
              const float* __restrict__ f0w, const float* __restrict__ f1w,
              const float* __restrict__ f2w, const float* __restrict__ e0w,
              const float* __restrict__ e1w, unsigned short* __restrict__ wtb)
{
    __shared__ __align__(16) unsigned short xs[4 * 128 * 8];
    int f = blockIdx.x;
    if (f < 480)
        conv1x1_body<128, 128, 0, false>(f, xs, x0, nullptr, w0,
            b0, nullptr, nullptr, nullptr, lat0b, 15360);
    else if (f < 600)
        conv1x1_body<256, 128, 0, false>(f - 480, xs, x1, nullptr, w1,
            b1, nullptr, nullptr, nullptr, lat1b, 3840);
    else if (f < 660)
        conv1x1_body<512, 64, 0, false>(f - 600, xs, x2, nullptr, w2,
            b2, nullptr, nullptr, nullptr, lat2p, 960);
    else {
        int base = (f - 660) * 1024 + threadIdx.x;
#pragma unroll
        for (int t = 0; t < 4; ++t) {
            int i = base + t * 256;            // < 239616 exactly
            float v;
            if (i < 110592) {
                int z = i / 36864;
                int rem = i - z * 36864;
                int tap = rem / 4096;          // 64*64
                int r2 = rem - tap * 4096;
                int co = r2 >> 6, ci = r2 & 63;
                const float* src = (z == 0) ? f0w : (z == 1 ? f1w : f2w);
                v = src[((size_t)co * 64 + ci) * 9 + tap];
            } else {
                int j = i - 110592;
                int z = j / 64512;
                int rem = j - z * 64512;
                int tap = rem / 7168;          // 112*64
                int r2 = rem - tap * 7168;
                int co = r2 >> 6, ci = r2 & 63;
                const float* src = z ? e1w : e0w;
                v = (co < 100) ? src[((size_t)co * 64 + ci) * 9 + tap] : 0.f;
            }
            wtb[i] = f2bf(v);
        }
    }
}

// ---------------------------------------------------------------------------
// CARAFE v8: channel-last everywhere.  src: uint4 staging (64B/px-half);
// logits: channel-last bf16 (25 taps in ~2 lines); base/dst: 8 consecutive
// u32 per (px, cs, cg).  bounds 4 (R4: 6 regressed).
// grid: (2w/16, 2h/16, B * CGS), block 256
// ---------------------------------------------------------------------------
template<int CGS>
__global__ __launch_bounds__(256, 4)
void carafe_kernel(const unsigned* __restrict__ srcp,
                   const unsigned short* __restrict__ logits_us,
                   const unsigned* __restrict__ basep, unsigned* __restrict__ dstp,
                   int h, int w)
{
    constexpr int SW = 12, NPX = 144;
    constexpr int CH = 64 / CGS;     // 32 channels handled per block
    constexpr int CS = CH + 4;
    __shared__ float ls[NPX * CS];

    int tid = threadIdx.x;
    int x0 = blockIdx.x * 16, y0 = blockIdx.y * 16;
    int b  = blockIdx.z / CGS;
    int cs = blockIdx.z % CGS;
    int H = 2 * h, W = 2 * w;
    int xs0 = (x0 >> 1) - 2, ys0 = (y0 >> 1) - 2;
    size_t hw = (size_t)h * w;
    const unsigned* sb = srcp + (size_t)b * hw * 32 + cs * 16;

    // stage: item = (p, g): uint4 of pairs cs*16+4g..+3 at src pixel p.
    for (int i = tid; i < NPX * 4; i += 256) {
        int p = i >> 2, g = i & 3;
        int yy = p / SW, xx = p - yy * SW;
        int sy = ys0 + yy, sx = xs0 + xx;
        uint4 u = make_uint4(0u, 0u, 0u, 0u);
        if (sy >= 0 && sy < h && sx >= 0 && sx < w)
            u = *(const uint4*)(sb + ((size_t)sy * w + sx) * 32 + g * 4);
        float* lq = &ls[p * CS + g * 8];
        lq[0] = __uint_as_float(u.x << 16); lq[1] = __uint_as_float(u.x & 0xffff0000u);
        lq[2] = __uint_as_float(u.y << 16); lq[3] = __uint_as_float(u.y & 0xffff0000u);
        lq[4] = __uint_as_float(u.z << 16); lq[5] = __uint_as_float(u.z & 0xffff0000u);
        lq[6] = __uint_as_float(u.w << 16); lq[7] = __uint_as_float(u.w & 0xffff0000u);
    }
    __syncthreads();

    int lx = tid & 15, ty = tid >> 4;
    int x = x0 + lx, y = y0 + ty;
    int xw = x >> 1, yh = y >> 1;
    int par = (y & 1) * 2 + (x & 1);

    const unsigned short* lp = logits_us + ((size_t)b * hw + (size_t)yh * w + xw) * 100 + par;
    float l[25];
    float mx = -1e30f;
#pragma unroll
    for (int k = 0; k < 25; ++k) {
        l[k] = bf2f(lp[4 * k]);
        mx = fmaxf(mx, l[k]);
    }
    float s = 0.f;
#pragma unroll
    for (int k = 0; k < 25; ++k) {
        l[k] = __expf(l[k] - mx);
        s += l[k];
    }
    float invs = 1.f / s;
#pragma unroll
    for (int k = 0; k < 25; ++k) l[k] *= invs;

    int pb = (yh - ys0 - 2) * SW + (xw - xs0 - 2);

#pragma unroll 1
    for (int cg = 0; cg < CH / 16; ++cg) {
        float acc[16];
#pragma unroll
        for (int c = 0; c < 16; ++c) acc[c] = 0.f;
#pragma unroll
        for (int k = 0; k < 25; ++k) {
            int ti = k / 5, tj = k - ti * 5;
            const float* q = &ls[(pb + ti * SW + tj) * CS + cg * 16];
            float wk = l[k];
#pragma unroll
            for (int c = 0; c < 16; ++c)
                acc[c] = fmaf(wk, q[c], acc[c]);
        }
        // base/dst: 8 consecutive u32 at (px, pair base cs*16+cg*8)
        size_t poff = (((size_t)b * H + y) * W + x) * 32 + cs * 16 + cg * 8;
        uint4 ba = *(const uint4*)(basep + poff);
        uint4 bb = *(const uint4*)(basep + poff + 4);
        unsigned bu[8] = {ba.x, ba.y, ba.z, ba.w, bb.x, bb.y, bb.z, bb.w};
        unsigned ou[8];
#pragma unroll
        for (int j = 0; j < 8; ++j) {
            float n0 = __uint_as_float(bu[j] << 16) + acc[2 * j];
            float n1 = __uint_as_float(bu[j] & 0xffff0000u) + acc[2 * j + 1];
            ou[j] = packbf(n0, n1);
        }
        *(uint4*)(dstp + poff)     = make_uint4(ou[0], ou[1], ou[2], ou[3]);
        *(uint4*)(dstp + poff + 4) = make_uint4(ou[4], ou[5], ou[6], ou[7]);
    }
}

// ---------------------------------------------------------------------------
extern "C" void kernel_launch(void* const* d_in, const int* in_sizes, int n_in,
                              void* d_out, int out_size, void* d_ws, size_t ws_size,
                              hipStream_t stream)
{
    const float* x0      = (const float*)d_in[0];
    const float* lat0_w  = (const float*)d_in[1];
    const float* lat0_b  = (const float*)d_in[2];
    const float* fpn0_w  = (const float*)d_in[3];
    const float* fpn0_b  = (const float*)d_in[4];
    const float* x1      = (const float*)d_in[5];
    const float* lat1_w  = (const float*)d_in[6];
    const float* lat1_b  = (const float*)d_in[7];
    const float* fpn1_w  = (const float*)d_in[8];
    const float* fpn1_b  = (const float*)d_in[9];
    const float* x2      = (const float*)d_in[10];
    const float* lat2_w  = (const float*)d_in[11];
    const float* lat2_b  = (const float*)d_in[12];
    const float* fpn2_w  = (const float*)d_in[13];
    const float* fpn2_b  = (const float*)d_in[14];
    const float* u0_comp_w = (const float*)d_in[15];
    const float* u0_enc_w  = (const float*)d_in[16];
    const float* u0_comp_g  = (const float*)d_in[17];
    const float* u0_comp_bt = (const float*)d_in[18];
    const float* u0_comp_m  = (const float*)d_in[19];
    const float* u0_comp_v  = (const float*)d_in[20];
    const float* u0_enc_g   = (const float*)d_in[21];
    const float* u0_enc_bt  = (const float*)d_in[22];
    const float* u0_enc_m   = (const float*)d_in[23];
    const float* u0_enc_v   = (const float*)d_in[24];
    const float* u1_comp_w = (const float*)d_in[25];
    const float* u1_enc_w  = (const float*)d_in[26];
    const float* u1_comp_g  = (const float*)d_in[27];
    const float* u1_comp_bt = (const float*)d_in[28];
    const float* u1_comp_m  = (const float*)d_in[29];
    const float* u1_comp_v  = (const float*)d_in[30];
    const float* u1_enc_g   = (const float*)d_in[31];
    const float* u1_enc_bt  = (const float*)d_in[32];
    const float* u1_enc_m   = (const float*)d_in[33];
    const float* u1_enc_v   = (const float*)d_in[34];

    float* out = (float*)d_out;
    const size_t OUT0 = 4ull * 64 * 96 * 160;   // 3,932,160
    const size_t OUT1 = 4ull * 64 * 48 * 80;    //   983,040
    const size_t OUT2 = 4ull * 64 * 24 * 40;    //   245,760
    float* out0 = out;
    float* out1 = out + OUT0;
    float* out2 = out + OUT0 + OUT1;

    // workspace (mirrors are channel-last [b][H][W][cp=32] u32):
    unsigned* lat0b = (unsigned*)d_ws;                      // 1,966,080 u32
    unsigned* lat1b = lat0b + 1966080;                      //   491,520 u32
    unsigned short* wtb = (unsigned short*)(lat1b + 491520); // 239,616 bf16
    unsigned short* wt_fpn0 = wtb;
    unsigned short* wt_fpn1 = wtb + 36864;
    unsigned short* wt_fpn2 = wtb + 73728;
    unsigned short* wt_enc0 = wtb + 110592;
    unsigned short* wt_enc1 = wtb + 175104;
    unsigned* lat0p = (unsigned*)(wtb + 239616);            // 1,966,080 u32
    unsigned* lat1p = lat0p + 1966080;                      //   491,520 u32
    unsigned* lat2p = lat1p + 491520;                       //   122,880 u32
    unsigned* compp = lat2p + 122880;                       //   491,520 u32 (max)
    // out0 region doubles as scratch (fpn0 overwrites it LAST):
    unsigned short* enc_us = (unsigned short*)(out0 + OUT1); // enc logits bf16 CL

    dim3 blk(256);

    // 1) laterals (full-K, bias folded, mirror out) + 3x3 weight prep backfill
    lat_prep<<<dim3(894), blk, 0, stream>>>(
        x0, lat0_w, lat0_b, lat0b,
        x1, lat1_w, lat1_b, lat1b,
        x2, lat2_w, lat2_b, lat2p,
        fpn0_w, fpn1_w, fpn2_w, u0_enc_w, u1_enc_w, wtb);

    // 2) CARAFE u1: comp1 -> enc1(bf16) + fpn2 backfill -> carafe1
    conv1x1_mfma<64, 32, 1, true><<<dim3(30, 1, 4), blk, 0, stream>>>(
        nullptr, lat2p, u1_comp_w, u1_comp_g, u1_comp_bt, u1_comp_m, u1_comp_v,
        compp, 24 * 40);
    enc_fpn<<<dim3(264), blk, 0, stream>>>(168,
        compp, wt_enc1, u1_enc_g, u1_enc_bt, u1_enc_m, u1_enc_v, enc_us, 24, 40, 3,
        lat2p, wt_fpn2, fpn2_b, out2, 24, 40, 3);
    carafe_kernel<2><<<dim3(5, 3, 8), blk, 0, stream>>>(lat2p, enc_us, lat1b, lat1p, 24, 40);

    // 3) CARAFE u0: comp0 -> enc0(bf16) + fpn1 backfill -> carafe0
    conv1x1_mfma<64, 32, 1, true><<<dim3(120, 1, 4), blk, 0, stream>>>(
        nullptr, lat1p, u0_comp_w, u0_comp_g, u0_comp_bt, u0_comp_m, u0_comp_v,
        compp, 48 * 80);
    enc_fpn<<<dim3(660), blk, 0, stream>>>(420,
        compp, wt_enc0, u0_enc_g, u0_enc_bt, u0_enc_m, u0_enc_v, enc_us, 48, 80, 5,
        lat1p, wt_fpn1, fpn1_b, out1, 48, 80, 5);
    carafe_kernel<2><<<dim3(10, 6, 8), blk, 0, stream>>>(lat1p, enc_us, lat0b, lat0p, 48, 80);

    // 4) final fpn: level0 only (960 blocks)
    fpn_multi<<<dim3(960), blk, 0, stream>>>(lat0p, wt_fpn0, fpn0_b, out0);
}